// Round 13
// baseline (451.565 us; speedup 1.0000x reference)
//
#include <hip/hip_runtime.h>

#define DIMN 2048
#define NH 16
#define HDN 128
#define SEQ 2048
#define BATCH 2
#define MROWS (BATCH * SEQ)  // 4096

typedef unsigned short u16;
using short8 = __attribute__((ext_vector_type(8))) short;
using f32x4 = __attribute__((ext_vector_type(4))) float;

__device__ __forceinline__ u16 f2bf(float f) {
  unsigned int x = __float_as_uint(f);
  unsigned int r = (x + 0x7fffu + ((x >> 16) & 1u)) >> 16;
  return (u16)r;
}
__device__ __forceinline__ float bf2f(u16 u) {
  return __uint_as_float(((unsigned int)u) << 16);
}

typedef const __attribute__((address_space(1))) void* gptr_t;
typedef __attribute__((address_space(3))) void* lptr_t;
__device__ __forceinline__ void gld16(const void* g, void* l) {
  __builtin_amdgcn_global_load_lds((gptr_t)g, (lptr_t)l, 16, 0, 0);
}
__device__ __forceinline__ void waitbar() {
  asm volatile("s_waitcnt vmcnt(0)" ::: "memory");
  __builtin_amdgcn_s_barrier();
  __builtin_amdgcn_sched_barrier(0);
}
__device__ __forceinline__ void barx() {
  asm volatile("" ::: "memory");
  __builtin_amdgcn_s_barrier();
  __builtin_amdgcn_sched_barrier(0);
}

// ---------------- f32 -> bf16 convert (all 6 tensors, one launch) ------------
__global__ void k_conv6(const float* __restrict__ s0, const float* __restrict__ s1,
                        const float* __restrict__ s2, const float* __restrict__ s3,
                        const float* __restrict__ s4, const float* __restrict__ s5,
                        u16* __restrict__ dst) {
  int i = (blockIdx.x * blockDim.x + threadIdx.x) * 4;
  const float* s;
  int off;
  if (i < (1 << 24)) {
    const int which = i >> 22;
    off = i & ((1 << 22) - 1);
    s = (which == 0) ? s0 : (which == 1) ? s1 : (which == 2) ? s2 : s3;
  } else {
    const int j = i - (1 << 24);
    off = j & ((1 << 23) - 1);
    s = (j >> 23) ? s5 : s4;
  }
  float4 v = *(const float4*)(s + off);
  ushort4 o;
  o.x = f2bf(v.x); o.y = f2bf(v.y); o.z = f2bf(v.z); o.w = f2bf(v.w);
  *(ushort4*)(dst + i) = o;
}

// ---------------- GEMM, BK=64 + XOR-swizzled LDS, fused epilogues ----------
// C[m][n] = sum_k A[m][k]*W[n][k] + bias[n].  128x128 tile, BK=64, single
// buffer (32KB), m-banded XCD swizzle: XCD x owns m-panels [4x,4x+4), walks
// n-major with the 4 m-blocks of each n-panel consecutive -> A-band (2MB)
// stays hot in the XCD-private L2, B-panel read 4x back-to-back.
// LDS tiles [128][64] with G4 XOR swizzle (chunk c of row r at physical
// c^(r&7)), staged via pre-swizzled global src (rule 21); zero conflicts
// (verified round 12).
// Wave (wm,wn) owns rows [wm*64,+64), cols {wn*32+(j&1)*16+(j>>1)*64}:
// rotate-half pair (d,d+64) = acc[i][j]/acc[i][j+2] -> RoPE intra-thread.
// MODE 1 (QKV): col group g = n0>>11 picks {A, bias, dest}: g<2 -> bias+RoPE
// -> Qh/Kh [B*H][S][HD]; g==2 -> bias -> Vt [B*H][HD][S] (direct transpose).
// MODE 0: plain f32 + bias (out proj).
template <int MODE>
__global__ __launch_bounds__(256, 4) void k_gemm(const u16* __restrict__ A0,
                                                 const u16* __restrict__ A1,
                                                 const u16* __restrict__ Wb,
                                                 const float* __restrict__ b0,
                                                 const float* __restrict__ b1,
                                                 const float* __restrict__ b2,
                                                 void* __restrict__ o0,
                                                 void* __restrict__ o1,
                                                 void* __restrict__ o2,
                                                 const float* __restrict__ cosT,
                                                 const float* __restrict__ sinT) {
  __shared__ u16 As[128][64];
  __shared__ u16 Bs[128][64];
  const int K = DIMN;
  const int tid = threadIdx.x;
  const int lane = tid & 63;
  const int w = tid >> 6;
  const int wm = w >> 1, wn = w & 1;
  const int kh = lane >> 4;

  // m-banded XCD mapping: xcd owns 4 contiguous m-panels, n-major order
  const int bid = blockIdx.x;
  const int xcd = bid & 7;
  const int r_ = bid >> 3;
  const int m0 = (xcd * 4 + (r_ & 3)) * 128;
  const int n0 = (r_ >> 2) * 128;

  const int g = (MODE == 1) ? (n0 >> 11) : 0;
  const u16* A = (MODE == 1 && g > 0) ? A1 : A0;
  const float* bias = (MODE == 1) ? ((g == 0) ? b0 : (g == 1) ? b1 : b2) : b0;
  const int nl = n0 & (DIMN - 1);  // col offset within group (head base)

  // staging: lane l -> row (w*32 + i*8 + (l>>3)), physical chunk (l&7);
  // global source supplies logical chunk (l&7)^(l>>3)
  const int lr = lane >> 3, l8 = lane & 7;
  const u16* gA = A + (size_t)(m0 + w * 32 + lr) * K + (l8 ^ lr) * 8;
  const u16* gB = Wb + (size_t)(n0 + w * 32 + lr) * K + (l8 ^ lr) * 8;

  f32x4 acc[4][4] = {};
  const int cb = lane & 15;
  const int sw = cb & 7;

  for (int k0 = 0; k0 < K; k0 += 64) {
    barx();  // prior compute's LDS reads complete before overwrite
#pragma unroll
    for (int i = 0; i < 4; ++i) {
      gld16(gA + (size_t)i * 8 * K + k0, &As[w * 32 + i * 8][0]);
      gld16(gB + (size_t)i * 8 * K + k0, &Bs[w * 32 + i * 8][0]);
    }
    waitbar();

#pragma unroll
    for (int ks = 0; ks < 2; ++ks) {
      const int ch = ((ks * 4 + kh) ^ sw) * 8;  // swizzled chunk, elem units
      short8 af[4], bfr[4];
#pragma unroll
      for (int i = 0; i < 4; ++i)
        af[i] = *(const short8*)&As[wm * 64 + i * 16 + cb][ch];
#pragma unroll
      for (int j = 0; j < 4; ++j)
        bfr[j] = *(const short8*)&Bs[wn * 32 + (j & 1) * 16 + (j >> 1) * 64 + cb][ch];
#pragma unroll
      for (int i = 0; i < 4; ++i)
#pragma unroll
        for (int j = 0; j < 4; ++j)
          acc[i][j] =
              __builtin_amdgcn_mfma_f32_16x16x32_bf16(af[i], bfr[j], acc[i][j], 0, 0, 0);
    }
  }

  const int rb = kh * 4;

  if (MODE == 0) {
    float* out = (float*)o0;
#pragma unroll
    for (int j = 0; j < 4; ++j) {
      const int col = n0 + wn * 32 + (j & 1) * 16 + (j >> 1) * 64 + cb;
      const float bv = bias[col];
#pragma unroll
      for (int i = 0; i < 4; ++i)
#pragma unroll
        for (int r = 0; r < 4; ++r) {
          const size_t row = (size_t)(m0 + wm * 64 + i * 16 + rb + r);
          out[row * DIMN + col] = acc[i][j][r] + bv;
        }
      __builtin_amdgcn_sched_barrier(0);
    }
  } else if (g == 2) {
    // V: bias, write DIRECTLY transposed to Vt [B*H][HD][S]
    u16* Vt = (u16*)o2;
    const int h_head = nl >> 7;
#pragma unroll
    for (int j = 0; j < 4; ++j) {
      const int d = wn * 32 + (j & 1) * 16 + (j >> 1) * 64 + cb;
      const float bv = bias[nl + d];
#pragma unroll
      for (int i = 0; i < 4; ++i) {
        const int row0 = m0 + wm * 64 + i * 16 + rb;  // 4 consecutive rows
        const int bg = row0 >> 11;
        const int s = row0 & (SEQ - 1);
        ushort4 o;
        o.x = f2bf(acc[i][j][0] + bv);
        o.y = f2bf(acc[i][j][1] + bv);
        o.z = f2bf(acc[i][j][2] + bv);
        o.w = f2bf(acc[i][j][3] + bv);
        *(ushort4*)(Vt + ((size_t)(bg * NH + h_head) * HDN + d) * SEQ + s) = o;
      }
      __builtin_amdgcn_sched_barrier(0);
    }
  } else {
    // Q/K: bias + RoPE (pair intra-thread), write [B*H][S][HD].
    u16* dst = (u16*)((g == 0) ? o0 : o1);
    const int h_head = nl >> 7;
    const int d0 = wn * 32 + cb;
    const float bv10 = bias[nl + d0], bv20 = bias[nl + d0 + 64];
    const float bv11 = bias[nl + d0 + 16], bv21 = bias[nl + d0 + 80];
#pragma unroll
    for (int i = 0; i < 4; ++i) {
#pragma unroll
      for (int r = 0; r < 4; ++r) {
        const int row = m0 + wm * 64 + i * 16 + rb + r;
        const int bg = row >> 11;
        const int s = row & (SEQ - 1);
        u16* base = dst + ((size_t)(bg * NH + h_head) * SEQ + s) * HDN;
        const float* cr = cosT + s * HDN;
        const float* sr = sinT + s * HDN;
#pragma unroll
        for (int jp = 0; jp < 2; ++jp) {
          const int d = d0 + jp * 16;  // d < 64
          float x1 = acc[i][jp][r] + (jp ? bv11 : bv10);
          float x2 = acc[i][jp + 2][r] + (jp ? bv21 : bv20);
          float c = cr[d], sn = sr[d];  // cos[d] == cos[d+64] (concat table)
          base[d] = f2bf(x1 * c - x2 * sn);
          base[d + 64] = f2bf(x2 * c + x1 * sn);
        }
      }
      __builtin_amdgcn_sched_barrier(0);
    }
  }
}

// ---------------- Flash attention (causal), v7: V direct from L2 -------------
// V staging DROPPED (Common-mistake #7 / m169): V is XCD-pinned (4 bh x 1MB
// per XCD L2), bv fragments read directly from global (16B/lane contiguous).
// Frees 32KB LDS -> 3 blocks/CU; staging writes + prefetch glds halved.
// K stays LDS-staged (double-buffered prefetch).  No online softmax (scores
// bounded); l = sum exp(s) via MFMA with ones-B.  Segs {p, 31-p} share one
// K sweep; shared tiles read bk once for both segments.
__global__ __launch_bounds__(256, 3) void k_attn(const u16* __restrict__ Qh,
                                                 const u16* __restrict__ Kh,
                                                 const u16* __restrict__ Vt,
                                                 u16* __restrict__ AO) {
  __shared__ u16 Ks[2][64 * 128];
  __shared__ u16 Ps[4][16][72];
  const int tid = threadIdx.x, lane = tid & 63, w = tid >> 6;

  const int i0 = blockIdx.x;
  const int xcd = i0 & 7;
  const int j = i0 >> 3;
  const int bh = xcd * 4 + (j >> 4);
  const int p = j & 15;

  const int b = bh >> 4, h = bh & 15;
  const int rb = (lane >> 4) * 4, cb = lane & 15, kh = lane >> 4;
  const int sw = cb & 7;

  int rK[4], cK[4];
#pragma unroll
  for (int i = 0; i < 4; ++i) {
    const int off = w * 4096 + i * 1024 + lane * 16;
    rK[i] = off >> 8;
    cK[i] = ((off >> 4) & 15) ^ (rK[i] & 7);
  }

  const u16* gK = Kh + (size_t)bh * SEQ * HDN;
  const u16* gV = Vt + (size_t)bh * HDN * SEQ;
  const float scale2 = 0.127517435f;  // (1/sqrt(128)) * log2(e)
  const short8 ones8 = {0x3F80, 0x3F80, 0x3F80, 0x3F80, 0x3F80, 0x3F80, 0x3F80, 0x3F80};

  auto stage = [&](int buf, int kv0) {
    u16* KsB = &Ks[buf][0] + w * 2048;
#pragma unroll
    for (int i = 0; i < 4; ++i)
      gld16(gK + (size_t)(kv0 + rK[i]) * HDN + cK[i] * 8, KsB + i * 512);
  };

  const int qiA = p, qiB = 31 - p;
  const int qwA = qiA * 64 + w * 16;
  const int qwB = qiB * 64 + w * 16;

  short8 aqA[4], aqB[4];
  {
    const u16* qpA = Qh + ((size_t)bh * SEQ + qwA + cb) * HDN + kh * 8;
    const u16* qpB = Qh + ((size_t)bh * SEQ + qwB + cb) * HDN + kh * 8;
#pragma unroll
    for (int ks = 0; ks < 4; ++ks) {
      aqA[ks] = *(const short8*)(qpA + ks * 32);
      aqB[ks] = *(const short8*)(qpB + ks * 32);
    }
  }

  f32x4 accA[8] = {}, accB[8] = {};
  f32x4 accLA = {}, accLB = {};

  auto expmask = [&](f32x4(&sc)[4], int qw, int kv0, bool masked) {
    if (masked) {
#pragma unroll
      for (int f = 0; f < 4; ++f) {
        const int kva = kv0 + f * 16 + cb;
#pragma unroll
        for (int r = 0; r < 4; ++r)
          sc[f][r] = (kva <= qw + rb + r) ? exp2f(sc[f][r] * scale2) : 0.f;
      }
    } else {
#pragma unroll
      for (int f = 0; f < 4; ++f)
#pragma unroll
        for (int r = 0; r < 4; ++r) sc[f][r] = exp2f(sc[f][r] * scale2);
    }
  };
  auto pbounce = [&](const f32x4(&sc)[4], short8(&pa)[2]) {
    asm volatile("" ::: "memory");
#pragma unroll
    for (int f = 0; f < 4; ++f)
#pragma unroll
      for (int r = 0; r < 4; ++r) Ps[w][rb + r][f * 16 + cb] = f2bf(sc[f][r]);
    asm volatile("" ::: "memory");
#pragma unroll
    for (int kk = 0; kk < 2; ++kk) pa[kk] = *(const short8*)&Ps[w][cb][kk * 32 + kh * 8];
    asm volatile("" ::: "memory");
  };

  auto tile_single = [&](int kv0, bool masked, const u16* KsB) {
    f32x4 sc[4] = {};
    __builtin_amdgcn_s_setprio(1);
#pragma unroll
    for (int f = 0; f < 4; ++f)
#pragma unroll
      for (int ks = 0; ks < 4; ++ks) {
        short8 bk = *(const short8*)(KsB + (f * 16 + cb) * 128 + (((ks * 4 + kh) ^ sw) * 8));
        sc[f] = __builtin_amdgcn_mfma_f32_16x16x32_bf16(aqB[ks], bk, sc[f], 0, 0, 0);
      }
    __builtin_amdgcn_s_setprio(0);
    expmask(sc, qwB, kv0, masked);
    short8 pa[2];
    pbounce(sc, pa);
    const u16* gVb = gV + kv0;
    __builtin_amdgcn_s_setprio(1);
#pragma unroll
    for (int nf = 0; nf < 8; ++nf)
#pragma unroll
      for (int kk = 0; kk < 2; ++kk) {
        short8 bv = *(const short8*)(gVb + (size_t)(nf * 16 + cb) * SEQ + kk * 32 + kh * 8);
        accB[nf] = __builtin_amdgcn_mfma_f32_16x16x32_bf16(pa[kk], bv, accB[nf], 0, 0, 0);
      }
#pragma unroll
    for (int kk = 0; kk < 2; ++kk)
      accLB = __builtin_amdgcn_mfma_f32_16x16x32_bf16(pa[kk], ones8, accLB, 0, 0, 0);
    __builtin_amdgcn_s_setprio(0);
  };

  auto tile_shared = [&](int kv0, bool maskA, const u16* KsB) {
    f32x4 scA[4] = {}, scB[4] = {};
    __builtin_amdgcn_s_setprio(1);
#pragma unroll
    for (int f = 0; f < 4; ++f)
#pragma unroll
      for (int ks = 0; ks < 4; ++ks) {
        short8 bk = *(const short8*)(KsB + (f * 16 + cb) * 128 + (((ks * 4 + kh) ^ sw) * 8));
        scB[f] = __builtin_amdgcn_mfma_f32_16x16x32_bf16(aqB[ks], bk, scB[f], 0, 0, 0);
        scA[f] = __builtin_amdgcn_mfma_f32_16x16x32_bf16(aqA[ks], bk, scA[f], 0, 0, 0);
      }
    __builtin_amdgcn_s_setprio(0);
    expmask(scB, qwB, kv0, false);
    expmask(scA, qwA, kv0, maskA);
    short8 paB[2], paA[2];
    pbounce(scB, paB);
    pbounce(scA, paA);
    const u16* gVb = gV + kv0;
    __builtin_amdgcn_s_setprio(1);
#pragma unroll
    for (int nf = 0; nf < 8; ++nf)
#pragma unroll
      for (int kk = 0; kk < 2; ++kk) {
        short8 bv = *(const short8*)(gVb + (size_t)(nf * 16 + cb) * SEQ + kk * 32 + kh * 8);
        accB[nf] = __builtin_amdgcn_mfma_f32_16x16x32_bf16(paB[kk], bv, accB[nf], 0, 0, 0);
        accA[nf] = __builtin_amdgcn_mfma_f32_16x16x32_bf16(paA[kk], bv, accA[nf], 0, 0, 0);
      }
#pragma unroll
    for (int kk = 0; kk < 2; ++kk) {
      accLB = __builtin_amdgcn_mfma_f32_16x16x32_bf16(paB[kk], ones8, accLB, 0, 0, 0);
      accLA = __builtin_amdgcn_mfma_f32_16x16x32_bf16(paA[kk], ones8, accLA, 0, 0, 0);
    }
    __builtin_amdgcn_s_setprio(0);
  };

  const int nt = qiB + 1;
  stage(0, 0);
  waitbar();
  int cur = 0;

  for (int t = 0; t < nt; ++t) {
    const int kv0 = t * 64;
    if (t + 1 < nt) stage(cur ^ 1, (t + 1) * 64);

    if (t <= qiA)
      tile_shared(kv0, t == qiA, &Ks[cur][0]);
    else
      tile_single(kv0, t == qiB, &Ks[cur][0]);

    waitbar();
    cur ^= 1;
  }

  auto epi = [&](f32x4(&accO)[8], f32x4& accL, int qw) {
    float inv[4];
#pragma unroll
    for (int r = 0; r < 4; ++r) inv[r] = 1.f / accL[r];
#pragma unroll
    for (int nf = 0; nf < 8; ++nf)
#pragma unroll
      for (int r = 0; r < 4; ++r) {
        const size_t row = (size_t)(b * SEQ + qw + rb + r);
        AO[row * DIMN + h * HDN + nf * 16 + cb] = f2bf(accO[nf][r] * inv[r]);
      }
  };
  epi(accA, accLA, qwA);
  epi(accB, accLB, qwB);
}

// ---------------- launch ----------------
extern "C" void kernel_launch(void* const* d_in, const int* in_sizes, int n_in,
                              void* d_out, int out_size, void* d_ws, size_t ws_size,
                              hipStream_t stream) {
  const float* query = (const float*)d_in[0];
  const float* key_value = (const float*)d_in[1];
  const float* cosT = (const float*)d_in[2];
  const float* sinT = (const float*)d_in[3];
  const float* wq = (const float*)d_in[4];
  const float* bq = (const float*)d_in[5];
  const float* wk = (const float*)d_in[6];
  const float* bk = (const float*)d_in[7];
  const float* wv = (const float*)d_in[8];
  const float* bv = (const float*)d_in[9];
  const float* wo = (const float*)d_in[10];
  const float* bo = (const float*)d_in[11];
  float* out = (float*)d_out;

  const size_t WB = (size_t)DIMN * DIMN * 2;
  const size_t XB = (size_t)MROWS * DIMN * 2;
  char* ws = (char*)d_ws;
  size_t off = 0;
  auto alloc = [&](size_t bytes) {
    char* p = ws + off;
    off += bytes;
    return p;
  };
  // wq..wv..xkv must stay contiguous (fused conv + QKV weight indexing).
  u16* wq_bf = (u16*)alloc(WB);
  u16* wk_bf = (u16*)alloc(WB);
  u16* wv_bf = (u16*)alloc(WB);
  u16* wo_bf = (u16*)alloc(WB);
  u16* xq_bf = (u16*)alloc(XB);
  u16* xkv_bf = (u16*)alloc(XB);
  u16* Qh = (u16*)alloc(XB);
  u16* Kh = (u16*)alloc(XB);
  u16* Vt = (u16*)alloc(XB);
  u16* AO = (u16*)alloc(XB);

  // all six f32->bf16 converts in one launch (dst regions contiguous)
  k_conv6<<<dim3(32768), dim3(256), 0, stream>>>(wq, wk, wv, wo, query, key_value, wq_bf);

  // fused QKV GEMM + bias + RoPE + layout/transpose (one dispatch, 1536 wg)
  k_gemm<1><<<dim3(1536), dim3(256), 0, stream>>>(xq_bf, xkv_bf, wq_bf, bq, bk, bv, Qh, Kh,
                                                  Vt, cosT, sinT);

  k_attn<<<dim3(512), 256, 0, stream>>>(Qh, Kh, Vt, AO);

  k_gemm<0><<<dim3(512), dim3(256), 0, stream>>>(AO, AO, wo_bf, bo, bo, bo, out, nullptr,
                                                 nullptr, nullptr, nullptr);
}

// Round 15
// 406.316 us; speedup vs baseline: 1.1114x; 1.1114x over previous
//
#include <hip/hip_runtime.h>

#define DIMN 2048
#define NH 16
#define HDN 128
#define SEQ 2048
#define BATCH 2
#define MROWS (BATCH * SEQ)  // 4096

typedef unsigned short u16;
using short8 = __attribute__((ext_vector_type(8))) short;
using f32x4 = __attribute__((ext_vector_type(4))) float;

__device__ __forceinline__ u16 f2bf(float f) {
  unsigned int x = __float_as_uint(f);
  unsigned int r = (x + 0x7fffu + ((x >> 16) & 1u)) >> 16;
  return (u16)r;
}
__device__ __forceinline__ float bf2f(u16 u) {
  return __uint_as_float(((unsigned int)u) << 16);
}

typedef const __attribute__((address_space(1))) void* gptr_t;
typedef __attribute__((address_space(3))) void* lptr_t;
__device__ __forceinline__ void gld16(const void* g, void* l) {
  __builtin_amdgcn_global_load_lds((gptr_t)g, (lptr_t)l, 16, 0, 0);
}
__device__ __forceinline__ void waitbar() {
  asm volatile("s_waitcnt vmcnt(0)" ::: "memory");
  __builtin_amdgcn_s_barrier();
  __builtin_amdgcn_sched_barrier(0);
}
__device__ __forceinline__ void barx() {
  asm volatile("" ::: "memory");
  __builtin_amdgcn_s_barrier();
  __builtin_amdgcn_sched_barrier(0);
}

// ---------------- f32 -> bf16 convert (all 6 tensors, one launch) ------------
__global__ void k_conv6(const float* __restrict__ s0, const float* __restrict__ s1,
                        const float* __restrict__ s2, const float* __restrict__ s3,
                        const float* __restrict__ s4, const float* __restrict__ s5,
                        u16* __restrict__ dst) {
  int i = (blockIdx.x * blockDim.x + threadIdx.x) * 4;
  const float* s;
  int off;
  if (i < (1 << 24)) {
    const int which = i >> 22;
    off = i & ((1 << 22) - 1);
    s = (which == 0) ? s0 : (which == 1) ? s1 : (which == 2) ? s2 : s3;
  } else {
    const int j = i - (1 << 24);
    off = j & ((1 << 23) - 1);
    s = (j >> 23) ? s5 : s4;
  }
  float4 v = *(const float4*)(s + off);
  ushort4 o;
  o.x = f2bf(v.x); o.y = f2bf(v.y); o.z = f2bf(v.z); o.w = f2bf(v.w);
  *(ushort4*)(dst + i) = o;
}

// ---------------- GEMM, BK=64 + XOR-swizzled LDS, fused epilogues ----------
// Round-12 proven: 128x128 tile, BK=64, single buffer (32KB), bijective XCD
// swizzle (id&7)*cpx+(id>>3).  LDS tiles [128][64] with G4 XOR swizzle
// (chunk c of row r at physical c^(r&7)), staged via pre-swizzled global
// src (rule 21); zero bank conflicts (verified round 12).
// Wave (wm,wn) owns rows [wm*64,+64), cols {wn*32+(j&1)*16+(j>>1)*64}:
// rotate-half pair (d,d+64) = acc[i][j]/acc[i][j+2] -> RoPE intra-thread.
// MODE 1 (QKV): col group g = n0>>11 picks {A, bias, dest}: g<2 -> bias+RoPE
// -> Qh/Kh [B*H][S][HD]; g==2 -> bias -> Vt [B*H][HD][S] (direct transpose).
// MODE 0: plain f32 + bias (out proj).
template <int MODE>
__global__ __launch_bounds__(256, 4) void k_gemm(const u16* __restrict__ A0,
                                                 const u16* __restrict__ A1,
                                                 const u16* __restrict__ Wb,
                                                 const float* __restrict__ b0,
                                                 const float* __restrict__ b1,
                                                 const float* __restrict__ b2,
                                                 void* __restrict__ o0,
                                                 void* __restrict__ o1,
                                                 void* __restrict__ o2,
                                                 const float* __restrict__ cosT,
                                                 const float* __restrict__ sinT) {
  __shared__ u16 As[128][64];
  __shared__ u16 Bs[128][64];
  const int K = DIMN;
  const int tid = threadIdx.x;
  const int lane = tid & 63;
  const int w = tid >> 6;
  const int wm = w >> 1, wn = w & 1;
  const int kh = lane >> 4;

  int id = blockIdx.x;
  const int nwg = gridDim.x;
  const int cpx = nwg >> 3;
  id = (id & 7) * cpx + (id >> 3);
  const int nbx = (MODE == 1) ? 48 : 16;
  const int n0 = (id % nbx) * 128;
  const int m0 = (id / nbx) * 128;

  const int g = (MODE == 1) ? (n0 >> 11) : 0;
  const u16* A = (MODE == 1 && g > 0) ? A1 : A0;
  const float* bias = (MODE == 1) ? ((g == 0) ? b0 : (g == 1) ? b1 : b2) : b0;
  const int nl = n0 & (DIMN - 1);  // col offset within group (head base)

  // staging: lane l -> row (w*32 + i*8 + (l>>3)), physical chunk (l&7);
  // global source supplies logical chunk (l&7)^(l>>3)
  const int lr = lane >> 3, l8 = lane & 7;
  const u16* gA = A + (size_t)(m0 + w * 32 + lr) * K + (l8 ^ lr) * 8;
  const u16* gB = Wb + (size_t)(n0 + w * 32 + lr) * K + (l8 ^ lr) * 8;

  f32x4 acc[4][4] = {};
  const int cb = lane & 15;
  const int sw = cb & 7;

  for (int k0 = 0; k0 < K; k0 += 64) {
    barx();  // prior compute's LDS reads complete before overwrite
#pragma unroll
    for (int i = 0; i < 4; ++i) {
      gld16(gA + (size_t)i * 8 * K + k0, &As[w * 32 + i * 8][0]);
      gld16(gB + (size_t)i * 8 * K + k0, &Bs[w * 32 + i * 8][0]);
    }
    waitbar();

#pragma unroll
    for (int ks = 0; ks < 2; ++ks) {
      const int ch = ((ks * 4 + kh) ^ sw) * 8;  // swizzled chunk, elem units
      short8 af[4], bfr[4];
#pragma unroll
      for (int i = 0; i < 4; ++i)
        af[i] = *(const short8*)&As[wm * 64 + i * 16 + cb][ch];
#pragma unroll
      for (int j = 0; j < 4; ++j)
        bfr[j] = *(const short8*)&Bs[wn * 32 + (j & 1) * 16 + (j >> 1) * 64 + cb][ch];
#pragma unroll
      for (int i = 0; i < 4; ++i)
#pragma unroll
        for (int j = 0; j < 4; ++j)
          acc[i][j] =
              __builtin_amdgcn_mfma_f32_16x16x32_bf16(af[i], bfr[j], acc[i][j], 0, 0, 0);
    }
  }

  const int rb = kh * 4;

  if (MODE == 0) {
    float* out = (float*)o0;
#pragma unroll
    for (int j = 0; j < 4; ++j) {
      const int col = n0 + wn * 32 + (j & 1) * 16 + (j >> 1) * 64 + cb;
      const float bv = bias[col];
#pragma unroll
      for (int i = 0; i < 4; ++i)
#pragma unroll
        for (int r = 0; r < 4; ++r) {
          const size_t row = (size_t)(m0 + wm * 64 + i * 16 + rb + r);
          out[row * DIMN + col] = acc[i][j][r] + bv;
        }
      __builtin_amdgcn_sched_barrier(0);
    }
  } else if (g == 2) {
    // V: bias, write DIRECTLY transposed to Vt [B*H][HD][S]
    u16* Vt = (u16*)o2;
    const int h_head = nl >> 7;
#pragma unroll
    for (int j = 0; j < 4; ++j) {
      const int d = wn * 32 + (j & 1) * 16 + (j >> 1) * 64 + cb;
      const float bv = bias[nl + d];
#pragma unroll
      for (int i = 0; i < 4; ++i) {
        const int row0 = m0 + wm * 64 + i * 16 + rb;  // 4 consecutive rows
        const int bg = row0 >> 11;
        const int s = row0 & (SEQ - 1);
        ushort4 o;
        o.x = f2bf(acc[i][j][0] + bv);
        o.y = f2bf(acc[i][j][1] + bv);
        o.z = f2bf(acc[i][j][2] + bv);
        o.w = f2bf(acc[i][j][3] + bv);
        *(ushort4*)(Vt + ((size_t)(bg * NH + h_head) * HDN + d) * SEQ + s) = o;
      }
      __builtin_amdgcn_sched_barrier(0);
    }
  } else {
    // Q/K: bias + RoPE (pair intra-thread), write [B*H][S][HD].
    u16* dst = (u16*)((g == 0) ? o0 : o1);
    const int h_head = nl >> 7;
    const int d0 = wn * 32 + cb;
    const float bv10 = bias[nl + d0], bv20 = bias[nl + d0 + 64];
    const float bv11 = bias[nl + d0 + 16], bv21 = bias[nl + d0 + 80];
#pragma unroll
    for (int i = 0; i < 4; ++i) {
#pragma unroll
      for (int r = 0; r < 4; ++r) {
        const int row = m0 + wm * 64 + i * 16 + rb + r;
        const int bg = row >> 11;
        const int s = row & (SEQ - 1);
        u16* base = dst + ((size_t)(bg * NH + h_head) * SEQ + s) * HDN;
        const float* cr = cosT + s * HDN;
        const float* sr = sinT + s * HDN;
#pragma unroll
        for (int jp = 0; jp < 2; ++jp) {
          const int d = d0 + jp * 16;  // d < 64
          float x1 = acc[i][jp][r] + (jp ? bv11 : bv10);
          float x2 = acc[i][jp + 2][r] + (jp ? bv21 : bv20);
          float c = cr[d], sn = sr[d];  // cos[d] == cos[d+64] (concat table)
          base[d] = f2bf(x1 * c - x2 * sn);
          base[d + 64] = f2bf(x2 * c + x1 * sn);
        }
      }
      __builtin_amdgcn_sched_barrier(0);
    }
  }
}

// ---------------- Flash attention (causal), v9 -------------------------------
// Round-14 NaN root cause: Ps[...][40] with 64-column writes (overflow).
// Fix: SPLIT P-bounce — write cols 0..31 (f=0,1), read pa[0]; reuse the same
// 16x32 buffer for cols 32..63 (f=2,3), read pa[1].  Intra-wave LDS is
// in-order, so per-wave write->read->overwrite is safe (same mechanism all
// passing rounds used).  Ps[4][16][40] is now correct by construction.
// LDS: Ks dbuf 32KB + Vs SINGLE 16KB + Ps 5KB = 54.3KB -> 3 blocks/CU.
// Per tile: stageV first (oldest loads), stageK(next); QK^T + softmax; then
// vmcnt(4) (V done, K-prefetch still in flight) + barrier; PV from Vs.
// No online softmax (scores bounded); l = sum exp2(s) via MFMA with ones-B.
// (bh,p) XCD-locality remap; segs {p, 31-p} share one K sweep; shared tiles
// read bk/bv once for both segments.
__global__ __launch_bounds__(256, 3) void k_attn(const u16* __restrict__ Qh,
                                                 const u16* __restrict__ Kh,
                                                 const u16* __restrict__ Vt,
                                                 u16* __restrict__ AO) {
  __shared__ u16 Ks[2][64 * 128];
  __shared__ u16 Vs[128 * 64];
  __shared__ u16 Ps[4][16][40];
  const int tid = threadIdx.x, lane = tid & 63, w = tid >> 6;

  const int i0 = blockIdx.x;
  const int xcd = i0 & 7;
  const int j = i0 >> 3;
  const int bh = xcd * 4 + (j >> 4);
  const int p = j & 15;

  const int b = bh >> 4, h = bh & 15;
  const int rb = (lane >> 4) * 4, cb = lane & 15, kh = lane >> 4;
  const int sw = cb & 7;

  int rK[4], cK[4], rV[4], cV[4];
#pragma unroll
  for (int i = 0; i < 4; ++i) {
    const int off = w * 4096 + i * 1024 + lane * 16;
    rK[i] = off >> 8;
    cK[i] = ((off >> 4) & 15) ^ (rK[i] & 7);
    rV[i] = off >> 7;
    cV[i] = ((off >> 4) & 7) ^ (rV[i] & 7);
  }

  const u16* gK = Kh + (size_t)bh * SEQ * HDN;
  const u16* gV = Vt + (size_t)bh * HDN * SEQ;
  const float scale2 = 0.127517435f;  // (1/sqrt(128)) * log2(e)
  const short8 ones8 = {0x3F80, 0x3F80, 0x3F80, 0x3F80, 0x3F80, 0x3F80, 0x3F80, 0x3F80};

  auto stageK = [&](int buf, int kv0) {
    u16* KsB = &Ks[buf][0] + w * 2048;
#pragma unroll
    for (int i = 0; i < 4; ++i)
      gld16(gK + (size_t)(kv0 + rK[i]) * HDN + cK[i] * 8, KsB + i * 512);
  };
  auto stageV = [&](int kv0) {
    u16* VsB = &Vs[0] + w * 2048;
#pragma unroll
    for (int i = 0; i < 4; ++i)
      gld16(gV + (size_t)rV[i] * SEQ + kv0 + cV[i] * 8, VsB + i * 512);
  };
  // mid-tile wait: V (oldest 4 loads/wave) done; K-prefetch may stay in flight
  auto midwait = [&](bool kin) {
    if (kin)
      asm volatile("s_waitcnt vmcnt(4)" ::: "memory");
    else
      asm volatile("s_waitcnt vmcnt(0)" ::: "memory");
    __builtin_amdgcn_s_barrier();
    __builtin_amdgcn_sched_barrier(0);
  };

  const int qiA = p, qiB = 31 - p;
  const int qwA = qiA * 64 + w * 16;
  const int qwB = qiB * 64 + w * 16;

  short8 aqA[4], aqB[4];
  {
    const u16* qpA = Qh + ((size_t)bh * SEQ + qwA + cb) * HDN + kh * 8;
    const u16* qpB = Qh + ((size_t)bh * SEQ + qwB + cb) * HDN + kh * 8;
#pragma unroll
    for (int ks = 0; ks < 4; ++ks) {
      aqA[ks] = *(const short8*)(qpA + ks * 32);
      aqB[ks] = *(const short8*)(qpB + ks * 32);
    }
  }

  f32x4 accA[8] = {}, accB[8] = {};
  f32x4 accLA = {}, accLB = {};

  auto expmask = [&](f32x4(&sc)[4], int qw, int kv0, bool masked) {
    if (masked) {
#pragma unroll
      for (int f = 0; f < 4; ++f) {
        const int kva = kv0 + f * 16 + cb;
#pragma unroll
        for (int r = 0; r < 4; ++r)
          sc[f][r] = (kva <= qw + rb + r) ? exp2f(sc[f][r] * scale2) : 0.f;
      }
    } else {
#pragma unroll
      for (int f = 0; f < 4; ++f)
#pragma unroll
        for (int r = 0; r < 4; ++r) sc[f][r] = exp2f(sc[f][r] * scale2);
    }
  };
  // split P bounce: 16x32 buffer reused for the two kk halves (cols 0..31
  // then 32..63); per-wave LDS ops are in-order.
  auto pbounce = [&](const f32x4(&sc)[4], short8(&pa)[2]) {
#pragma unroll
    for (int kk = 0; kk < 2; ++kk) {
      asm volatile("" ::: "memory");
#pragma unroll
      for (int f = 0; f < 2; ++f)
#pragma unroll
        for (int r = 0; r < 4; ++r)
          Ps[w][rb + r][f * 16 + cb] = f2bf(sc[kk * 2 + f][r]);
      asm volatile("" ::: "memory");
      pa[kk] = *(const short8*)&Ps[w][cb][kh * 8];
      asm volatile("" ::: "memory");
    }
  };

  // single-segment tile (segB only)
  auto tile_single = [&](int kv0, bool masked, const u16* KsB, bool kin) {
    f32x4 sc[4] = {};
    __builtin_amdgcn_s_setprio(1);
#pragma unroll
    for (int f = 0; f < 4; ++f)
#pragma unroll
      for (int ks = 0; ks < 4; ++ks) {
        short8 bk = *(const short8*)(KsB + (f * 16 + cb) * 128 + (((ks * 4 + kh) ^ sw) * 8));
        sc[f] = __builtin_amdgcn_mfma_f32_16x16x32_bf16(aqB[ks], bk, sc[f], 0, 0, 0);
      }
    __builtin_amdgcn_s_setprio(0);
    expmask(sc, qwB, kv0, masked);
    short8 pa[2];
    pbounce(sc, pa);
    midwait(kin);
    __builtin_amdgcn_s_setprio(1);
#pragma unroll
    for (int nf = 0; nf < 8; ++nf)
#pragma unroll
      for (int kk = 0; kk < 2; ++kk) {
        short8 bv = *(const short8*)(&Vs[0] + (nf * 16 + cb) * 64 + (((kk * 4 + kh) ^ sw) * 8));
        accB[nf] = __builtin_amdgcn_mfma_f32_16x16x32_bf16(pa[kk], bv, accB[nf], 0, 0, 0);
      }
#pragma unroll
    for (int kk = 0; kk < 2; ++kk)
      accLB = __builtin_amdgcn_mfma_f32_16x16x32_bf16(pa[kk], ones8, accLB, 0, 0, 0);
    __builtin_amdgcn_s_setprio(0);
  };

  // shared tile: one bk/bv read feeds both segments; segB provably unmasked.
  auto tile_shared = [&](int kv0, bool maskA, const u16* KsB, bool kin) {
    f32x4 scA[4] = {}, scB[4] = {};
    __builtin_amdgcn_s_setprio(1);
#pragma unroll
    for (int f = 0; f < 4; ++f)
#pragma unroll
      for (int ks = 0; ks < 4; ++ks) {
        short8 bk = *(const short8*)(KsB + (f * 16 + cb) * 128 + (((ks * 4 + kh) ^ sw) * 8));
        scB[f] = __builtin_amdgcn_mfma_f32_16x16x32_bf16(aqB[ks], bk, scB[f], 0, 0, 0);
        scA[f] = __builtin_amdgcn_mfma_f32_16x16x32_bf16(aqA[ks], bk, scA[f], 0, 0, 0);
      }
    __builtin_amdgcn_s_setprio(0);
    expmask(scB, qwB, kv0, false);
    expmask(scA, qwA, kv0, maskA);
    short8 paB[2], paA[2];
    pbounce(scB, paB);
    pbounce(scA, paA);
    midwait(kin);
    __builtin_amdgcn_s_setprio(1);
#pragma unroll
    for (int nf = 0; nf < 8; ++nf)
#pragma unroll
      for (int kk = 0; kk < 2; ++kk) {
        short8 bv = *(const short8*)(&Vs[0] + (nf * 16 + cb) * 64 + (((kk * 4 + kh) ^ sw) * 8));
        accB[nf] = __builtin_amdgcn_mfma_f32_16x16x32_bf16(paB[kk], bv, accB[nf], 0, 0, 0);
        accA[nf] = __builtin_amdgcn_mfma_f32_16x16x32_bf16(paA[kk], bv, accA[nf], 0, 0, 0);
      }
#pragma unroll
    for (int kk = 0; kk < 2; ++kk) {
      accLB = __builtin_amdgcn_mfma_f32_16x16x32_bf16(paB[kk], ones8, accLB, 0, 0, 0);
      accLA = __builtin_amdgcn_mfma_f32_16x16x32_bf16(paA[kk], ones8, accLA, 0, 0, 0);
    }
    __builtin_amdgcn_s_setprio(0);
  };

  const int nt = qiB + 1;
  stageK(0, 0);
  waitbar();
  int cur = 0;

  for (int t = 0; t < nt; ++t) {
    const int kv0 = t * 64;
    const bool kin = (t + 1 < nt);
    stageV(kv0);                         // 4 loads/wave (oldest)
    if (kin) stageK(cur ^ 1, kv0 + 64);  // +4 loads (stay in flight past midwait)

    if (t <= qiA)
      tile_shared(kv0, t == qiA, &Ks[cur][0], kin);
    else
      tile_single(kv0, t == qiB, &Ks[cur][0], kin);

    waitbar();  // drain K-prefetch; all Vs/Ks readers done before overwrite
    cur ^= 1;
  }

  auto epi = [&](f32x4(&accO)[8], f32x4& accL, int qw) {
    float inv[4];
#pragma unroll
    for (int r = 0; r < 4; ++r) inv[r] = 1.f / accL[r];
#pragma unroll
    for (int nf = 0; nf < 8; ++nf)
#pragma unroll
      for (int r = 0; r < 4; ++r) {
        const size_t row = (size_t)(b * SEQ + qw + rb + r);
        AO[row * DIMN + h * HDN + nf * 16 + cb] = f2bf(accO[nf][r] * inv[r]);
      }
  };
  epi(accA, accLA, qwA);
  epi(accB, accLB, qwB);
}

// ---------------- launch ----------------
extern "C" void kernel_launch(void* const* d_in, const int* in_sizes, int n_in,
                              void* d_out, int out_size, void* d_ws, size_t ws_size,
                              hipStream_t stream) {
  const float* query = (const float*)d_in[0];
  const float* key_value = (const float*)d_in[1];
  const float* cosT = (const float*)d_in[2];
  const float* sinT = (const float*)d_in[3];
  const float* wq = (const float*)d_in[4];
  const float* bq = (const float*)d_in[5];
  const float* wk = (const float*)d_in[6];
  const float* bk = (const float*)d_in[7];
  const float* wv = (const float*)d_in[8];
  const float* bv = (const float*)d_in[9];
  const float* wo = (const float*)d_in[10];
  const float* bo = (const float*)d_in[11];
  float* out = (float*)d_out;

  const size_t WB = (size_t)DIMN * DIMN * 2;
  const size_t XB = (size_t)MROWS * DIMN * 2;
  char* ws = (char*)d_ws;
  size_t off = 0;
  auto alloc = [&](size_t bytes) {
    char* p = ws + off;
    off += bytes;
    return p;
  };
  // wq..wv..xkv must stay contiguous (fused conv + QKV weight indexing).
  u16* wq_bf = (u16*)alloc(WB);
  u16* wk_bf = (u16*)alloc(WB);
  u16* wv_bf = (u16*)alloc(WB);
  u16* wo_bf = (u16*)alloc(WB);
  u16* xq_bf = (u16*)alloc(XB);
  u16* xkv_bf = (u16*)alloc(XB);
  u16* Qh = (u16*)alloc(XB);
  u16* Kh = (u16*)alloc(XB);
  u16* Vt = (u16*)alloc(XB);
  u16* AO = (u16*)alloc(XB);

  // all six f32->bf16 converts in one launch (dst regions contiguous)
  k_conv6<<<dim3(32768), dim3(256), 0, stream>>>(wq, wk, wv, wo, query, key_value, wq_bf);

  // fused QKV GEMM + bias + RoPE + layout/transpose (one dispatch, 1536 wg)
  k_gemm<1><<<dim3(1536), dim3(256), 0, stream>>>(xq_bf, xkv_bf, wq_bf, bq, bk, bv, Qh, Kh,
                                                  Vt, cosT, sinT);

  k_attn<<<dim3(512), 256, 0, stream>>>(Qh, Kh, Vt, AO);

  k_gemm<0><<<dim3(512), dim3(256), 0, stream>>>(AO, AO, wo_bf, bo, bo, bo, out, nullptr,
                                                 nullptr, nullptr, nullptr);
}

// Round 16
// 272.927 us; speedup vs baseline: 1.6545x; 1.4887x over previous
//
#include <hip/hip_runtime.h>

#define DIMN 2048
#define NH 16
#define HDN 128
#define SEQ 2048
#define BATCH 2
#define MROWS (BATCH * SEQ)  // 4096

typedef unsigned short u16;
using short8 = __attribute__((ext_vector_type(8))) short;
using f32x4 = __attribute__((ext_vector_type(4))) float;

__device__ __forceinline__ u16 f2bf(float f) {
  unsigned int x = __float_as_uint(f);
  unsigned int r = (x + 0x7fffu + ((x >> 16) & 1u)) >> 16;
  return (u16)r;
}
__device__ __forceinline__ float bf2f(u16 u) {
  return __uint_as_float(((unsigned int)u) << 16);
}

typedef const __attribute__((address_space(1))) void* gptr_t;
typedef __attribute__((address_space(3))) void* lptr_t;
__device__ __forceinline__ void gld16(const void* g, void* l) {
  __builtin_amdgcn_global_load_lds((gptr_t)g, (lptr_t)l, 16, 0, 0);
}
__device__ __forceinline__ void waitbar() {
  asm volatile("s_waitcnt vmcnt(0)" ::: "memory");
  __builtin_amdgcn_s_barrier();
  __builtin_amdgcn_sched_barrier(0);
}
__device__ __forceinline__ void barx() {
  asm volatile("" ::: "memory");
  __builtin_amdgcn_s_barrier();
  __builtin_amdgcn_sched_barrier(0);
}

// ---------------- f32 -> bf16 convert (all 6 tensors, one launch) ------------
__global__ void k_conv6(const float* __restrict__ s0, const float* __restrict__ s1,
                        const float* __restrict__ s2, const float* __restrict__ s3,
                        const float* __restrict__ s4, const float* __restrict__ s5,
                        u16* __restrict__ dst) {
  int i = (blockIdx.x * blockDim.x + threadIdx.x) * 4;
  const float* s;
  int off;
  if (i < (1 << 24)) {
    const int which = i >> 22;
    off = i & ((1 << 22) - 1);
    s = (which == 0) ? s0 : (which == 1) ? s1 : (which == 2) ? s2 : s3;
  } else {
    const int j = i - (1 << 24);
    off = j & ((1 << 23) - 1);
    s = (j >> 23) ? s5 : s4;
  }
  float4 v = *(const float4*)(s + off);
  ushort4 o;
  o.x = f2bf(v.x); o.y = f2bf(v.y); o.z = f2bf(v.z); o.w = f2bf(v.w);
  *(ushort4*)(dst + i) = o;
}

// ---------------- GEMM, BK=64 + XOR-swizzled LDS, fused epilogues ----------
// Round-12 proven: 128x128 tile, BK=64, single buffer (32KB), bijective XCD
// swizzle (id&7)*cpx+(id>>3).  LDS tiles [128][64] with G4 XOR swizzle
// (chunk c of row r at physical c^(r&7)), staged via pre-swizzled global
// src (rule 21); zero bank conflicts (verified round 12).
// Wave (wm,wn) owns rows [wm*64,+64), cols {wn*32+(j&1)*16+(j>>1)*64}:
// rotate-half pair (d,d+64) = acc[i][j]/acc[i][j+2] -> RoPE intra-thread.
// MODE 1 (QKV): col group g = n0>>11 picks {A, bias, dest}: g<2 -> bias+RoPE
// -> Qh/Kh [B*H][S][HD]; g==2 -> bias -> Vt [B*H][HD][S] (direct transpose).
// MODE 0: plain f32 + bias (out proj).
template <int MODE>
__global__ __launch_bounds__(256, 4) void k_gemm(const u16* __restrict__ A0,
                                                 const u16* __restrict__ A1,
                                                 const u16* __restrict__ Wb,
                                                 const float* __restrict__ b0,
                                                 const float* __restrict__ b1,
                                                 const float* __restrict__ b2,
                                                 void* __restrict__ o0,
                                                 void* __restrict__ o1,
                                                 void* __restrict__ o2,
                                                 const float* __restrict__ cosT,
                                                 const float* __restrict__ sinT) {
  __shared__ u16 As[128][64];
  __shared__ u16 Bs[128][64];
  const int K = DIMN;
  const int tid = threadIdx.x;
  const int lane = tid & 63;
  const int w = tid >> 6;
  const int wm = w >> 1, wn = w & 1;
  const int kh = lane >> 4;

  int id = blockIdx.x;
  const int nwg = gridDim.x;
  const int cpx = nwg >> 3;
  id = (id & 7) * cpx + (id >> 3);
  const int nbx = (MODE == 1) ? 48 : 16;
  const int n0 = (id % nbx) * 128;
  const int m0 = (id / nbx) * 128;

  const int g = (MODE == 1) ? (n0 >> 11) : 0;
  const u16* A = (MODE == 1 && g > 0) ? A1 : A0;
  const float* bias = (MODE == 1) ? ((g == 0) ? b0 : (g == 1) ? b1 : b2) : b0;
  const int nl = n0 & (DIMN - 1);  // col offset within group (head base)

  // staging: lane l -> row (w*32 + i*8 + (l>>3)), physical chunk (l&7);
  // global source supplies logical chunk (l&7)^(l>>3)
  const int lr = lane >> 3, l8 = lane & 7;
  const u16* gA = A + (size_t)(m0 + w * 32 + lr) * K + (l8 ^ lr) * 8;
  const u16* gB = Wb + (size_t)(n0 + w * 32 + lr) * K + (l8 ^ lr) * 8;

  f32x4 acc[4][4] = {};
  const int cb = lane & 15;
  const int sw = cb & 7;

  for (int k0 = 0; k0 < K; k0 += 64) {
    barx();  // prior compute's LDS reads complete before overwrite
#pragma unroll
    for (int i = 0; i < 4; ++i) {
      gld16(gA + (size_t)i * 8 * K + k0, &As[w * 32 + i * 8][0]);
      gld16(gB + (size_t)i * 8 * K + k0, &Bs[w * 32 + i * 8][0]);
    }
    waitbar();

#pragma unroll
    for (int ks = 0; ks < 2; ++ks) {
      const int ch = ((ks * 4 + kh) ^ sw) * 8;  // swizzled chunk, elem units
      short8 af[4], bfr[4];
#pragma unroll
      for (int i = 0; i < 4; ++i)
        af[i] = *(const short8*)&As[wm * 64 + i * 16 + cb][ch];
#pragma unroll
      for (int j = 0; j < 4; ++j)
        bfr[j] = *(const short8*)&Bs[wn * 32 + (j & 1) * 16 + (j >> 1) * 64 + cb][ch];
#pragma unroll
      for (int i = 0; i < 4; ++i)
#pragma unroll
        for (int j = 0; j < 4; ++j)
          acc[i][j] =
              __builtin_amdgcn_mfma_f32_16x16x32_bf16(af[i], bfr[j], acc[i][j], 0, 0, 0);
    }
  }

  const int rb = kh * 4;

  if (MODE == 0) {
    float* out = (float*)o0;
#pragma unroll
    for (int j = 0; j < 4; ++j) {
      const int col = n0 + wn * 32 + (j & 1) * 16 + (j >> 1) * 64 + cb;
      const float bv = bias[col];
#pragma unroll
      for (int i = 0; i < 4; ++i)
#pragma unroll
        for (int r = 0; r < 4; ++r) {
          const size_t row = (size_t)(m0 + wm * 64 + i * 16 + rb + r);
          out[row * DIMN + col] = acc[i][j][r] + bv;
        }
      __builtin_amdgcn_sched_barrier(0);
    }
  } else if (g == 2) {
    // V: bias, write DIRECTLY transposed to Vt [B*H][HD][S]
    u16* Vt = (u16*)o2;
    const int h_head = nl >> 7;
#pragma unroll
    for (int j = 0; j < 4; ++j) {
      const int d = wn * 32 + (j & 1) * 16 + (j >> 1) * 64 + cb;
      const float bv = bias[nl + d];
#pragma unroll
      for (int i = 0; i < 4; ++i) {
        const int row0 = m0 + wm * 64 + i * 16 + rb;  // 4 consecutive rows
        const int bg = row0 >> 11;
        const int s = row0 & (SEQ - 1);
        ushort4 o;
        o.x = f2bf(acc[i][j][0] + bv);
        o.y = f2bf(acc[i][j][1] + bv);
        o.z = f2bf(acc[i][j][2] + bv);
        o.w = f2bf(acc[i][j][3] + bv);
        *(ushort4*)(Vt + ((size_t)(bg * NH + h_head) * HDN + d) * SEQ + s) = o;
      }
      __builtin_amdgcn_sched_barrier(0);
    }
  } else {
    // Q/K: bias + RoPE (pair intra-thread), write [B*H][S][HD].
    u16* dst = (u16*)((g == 0) ? o0 : o1);
    const int h_head = nl >> 7;
    const int d0 = wn * 32 + cb;
    const float bv10 = bias[nl + d0], bv20 = bias[nl + d0 + 64];
    const float bv11 = bias[nl + d0 + 16], bv21 = bias[nl + d0 + 80];
#pragma unroll
    for (int i = 0; i < 4; ++i) {
#pragma unroll
      for (int r = 0; r < 4; ++r) {
        const int row = m0 + wm * 64 + i * 16 + rb + r;
        const int bg = row >> 11;
        const int s = row & (SEQ - 1);
        u16* base = dst + ((size_t)(bg * NH + h_head) * SEQ + s) * HDN;
        const float* cr = cosT + s * HDN;
        const float* sr = sinT + s * HDN;
#pragma unroll
        for (int jp = 0; jp < 2; ++jp) {
          const int d = d0 + jp * 16;  // d < 64
          float x1 = acc[i][jp][r] + (jp ? bv11 : bv10);
          float x2 = acc[i][jp + 2][r] + (jp ? bv21 : bv20);
          float c = cr[d], sn = sr[d];  // cos[d] == cos[d+64] (concat table)
          base[d] = f2bf(x1 * c - x2 * sn);
          base[d + 64] = f2bf(x2 * c + x1 * sn);
        }
      }
      __builtin_amdgcn_sched_barrier(0);
    }
  }
}

// ---------------- Flash attention (causal), round-12 proven (v6 + exp2f) -----
// __launch_bounds__(256,2): rounds 13/15 proved (256,3) spills accumulators
// to scratch (WRITE_SIZE 168-415MB, 3x slowdown) — 2 blocks/CU is the spill-
// free occupancy for this register footprint.  K/V double-buffered with
// 1-deep prefetch; no online softmax (scores bounded); l via MFMA ones-B;
// (bh,p) XCD-locality remap; segs {p, 31-p} share one K/V sweep; shared
// tiles read bk/bv once for both segments.
__global__ __launch_bounds__(256, 2) void k_attn(const u16* __restrict__ Qh,
                                                 const u16* __restrict__ Kh,
                                                 const u16* __restrict__ Vt,
                                                 u16* __restrict__ AO) {
  __shared__ u16 Ks[2][64 * 128];
  __shared__ u16 Vs[2][128 * 64];
  __shared__ u16 Ps[4][16][72];
  const int tid = threadIdx.x, lane = tid & 63, w = tid >> 6;

  const int i0 = blockIdx.x;
  const int xcd = i0 & 7;
  const int j = i0 >> 3;
  const int bh = xcd * 4 + (j >> 4);
  const int p = j & 15;

  const int b = bh >> 4, h = bh & 15;
  const int rb = (lane >> 4) * 4, cb = lane & 15, kh = lane >> 4;
  const int sw = cb & 7;

  int rK[4], cK[4], rV[4], cV[4];
#pragma unroll
  for (int i = 0; i < 4; ++i) {
    const int off = w * 4096 + i * 1024 + lane * 16;
    rK[i] = off >> 8;
    cK[i] = ((off >> 4) & 15) ^ (rK[i] & 7);
    rV[i] = off >> 7;
    cV[i] = ((off >> 4) & 7) ^ (rV[i] & 7);
  }

  const u16* gK = Kh + (size_t)bh * SEQ * HDN;
  const u16* gV = Vt + (size_t)bh * HDN * SEQ;
  const float scale2 = 0.127517435f;  // (1/sqrt(128)) * log2(e)
  const short8 ones8 = {0x3F80, 0x3F80, 0x3F80, 0x3F80, 0x3F80, 0x3F80, 0x3F80, 0x3F80};

  auto stage = [&](int buf, int kv0) {
    u16* KsB = &Ks[buf][0] + w * 2048;
    u16* VsB = &Vs[buf][0] + w * 2048;
#pragma unroll
    for (int i = 0; i < 4; ++i) {
      gld16(gK + (size_t)(kv0 + rK[i]) * HDN + cK[i] * 8, KsB + i * 512);
      gld16(gV + (size_t)rV[i] * SEQ + kv0 + cV[i] * 8, VsB + i * 512);
    }
  };

  const int qiA = p, qiB = 31 - p;
  const int qwA = qiA * 64 + w * 16;
  const int qwB = qiB * 64 + w * 16;

  short8 aqA[4], aqB[4];
  {
    const u16* qpA = Qh + ((size_t)bh * SEQ + qwA + cb) * HDN + kh * 8;
    const u16* qpB = Qh + ((size_t)bh * SEQ + qwB + cb) * HDN + kh * 8;
#pragma unroll
    for (int ks = 0; ks < 4; ++ks) {
      aqA[ks] = *(const short8*)(qpA + ks * 32);
      aqB[ks] = *(const short8*)(qpB + ks * 32);
    }
  }

  f32x4 accA[8] = {}, accB[8] = {};
  f32x4 accLA = {}, accLB = {};

  auto expmask = [&](f32x4(&sc)[4], int qw, int kv0, bool masked) {
    if (masked) {
#pragma unroll
      for (int f = 0; f < 4; ++f) {
        const int kva = kv0 + f * 16 + cb;
#pragma unroll
        for (int r = 0; r < 4; ++r)
          sc[f][r] = (kva <= qw + rb + r) ? exp2f(sc[f][r] * scale2) : 0.f;
      }
    } else {
#pragma unroll
      for (int f = 0; f < 4; ++f)
#pragma unroll
        for (int r = 0; r < 4; ++r) sc[f][r] = exp2f(sc[f][r] * scale2);
    }
  };
  auto pbounce = [&](const f32x4(&sc)[4], short8(&pa)[2]) {
    asm volatile("" ::: "memory");
#pragma unroll
    for (int f = 0; f < 4; ++f)
#pragma unroll
      for (int r = 0; r < 4; ++r) Ps[w][rb + r][f * 16 + cb] = f2bf(sc[f][r]);
    asm volatile("" ::: "memory");
#pragma unroll
    for (int kk = 0; kk < 2; ++kk) pa[kk] = *(const short8*)&Ps[w][cb][kk * 32 + kh * 8];
    asm volatile("" ::: "memory");
  };

  auto tile_single = [&](int kv0, bool masked, const u16* KsB, const u16* VsB) {
    f32x4 sc[4] = {};
    __builtin_amdgcn_s_setprio(1);
#pragma unroll
    for (int f = 0; f < 4; ++f)
#pragma unroll
      for (int ks = 0; ks < 4; ++ks) {
        short8 bk = *(const short8*)(KsB + (f * 16 + cb) * 128 + (((ks * 4 + kh) ^ sw) * 8));
        sc[f] = __builtin_amdgcn_mfma_f32_16x16x32_bf16(aqB[ks], bk, sc[f], 0, 0, 0);
      }
    __builtin_amdgcn_s_setprio(0);
    expmask(sc, qwB, kv0, masked);
    short8 pa[2];
    pbounce(sc, pa);
    __builtin_amdgcn_s_setprio(1);
#pragma unroll
    for (int nf = 0; nf < 8; ++nf)
#pragma unroll
      for (int kk = 0; kk < 2; ++kk) {
        short8 bv = *(const short8*)(VsB + (nf * 16 + cb) * 64 + (((kk * 4 + kh) ^ sw) * 8));
        accB[nf] = __builtin_amdgcn_mfma_f32_16x16x32_bf16(pa[kk], bv, accB[nf], 0, 0, 0);
      }
#pragma unroll
    for (int kk = 0; kk < 2; ++kk)
      accLB = __builtin_amdgcn_mfma_f32_16x16x32_bf16(pa[kk], ones8, accLB, 0, 0, 0);
    __builtin_amdgcn_s_setprio(0);
  };

  auto tile_shared = [&](int kv0, bool maskA, const u16* KsB, const u16* VsB) {
    f32x4 scA[4] = {}, scB[4] = {};
    __builtin_amdgcn_s_setprio(1);
#pragma unroll
    for (int f = 0; f < 4; ++f)
#pragma unroll
      for (int ks = 0; ks < 4; ++ks) {
        short8 bk = *(const short8*)(KsB + (f * 16 + cb) * 128 + (((ks * 4 + kh) ^ sw) * 8));
        scB[f] = __builtin_amdgcn_mfma_f32_16x16x32_bf16(aqB[ks], bk, scB[f], 0, 0, 0);
        scA[f] = __builtin_amdgcn_mfma_f32_16x16x32_bf16(aqA[ks], bk, scA[f], 0, 0, 0);
      }
    __builtin_amdgcn_s_setprio(0);
    expmask(scB, qwB, kv0, false);
    expmask(scA, qwA, kv0, maskA);
    short8 paB[2], paA[2];
    pbounce(scB, paB);
    pbounce(scA, paA);
    __builtin_amdgcn_s_setprio(1);
#pragma unroll
    for (int nf = 0; nf < 8; ++nf)
#pragma unroll
      for (int kk = 0; kk < 2; ++kk) {
        short8 bv = *(const short8*)(VsB + (nf * 16 + cb) * 64 + (((kk * 4 + kh) ^ sw) * 8));
        accB[nf] = __builtin_amdgcn_mfma_f32_16x16x32_bf16(paB[kk], bv, accB[nf], 0, 0, 0);
        accA[nf] = __builtin_amdgcn_mfma_f32_16x16x32_bf16(paA[kk], bv, accA[nf], 0, 0, 0);
      }
#pragma unroll
    for (int kk = 0; kk < 2; ++kk) {
      accLB = __builtin_amdgcn_mfma_f32_16x16x32_bf16(paB[kk], ones8, accLB, 0, 0, 0);
      accLA = __builtin_amdgcn_mfma_f32_16x16x32_bf16(paA[kk], ones8, accLA, 0, 0, 0);
    }
    __builtin_amdgcn_s_setprio(0);
  };

  const int nt = qiB + 1;
  stage(0, 0);
  waitbar();
  int cur = 0;

  for (int t = 0; t < nt; ++t) {
    const int kv0 = t * 64;
    if (t + 1 < nt) stage(cur ^ 1, (t + 1) * 64);

    if (t <= qiA)
      tile_shared(kv0, t == qiA, &Ks[cur][0], &Vs[cur][0]);
    else
      tile_single(kv0, t == qiB, &Ks[cur][0], &Vs[cur][0]);

    waitbar();
    cur ^= 1;
  }

  auto epi = [&](f32x4(&accO)[8], f32x4& accL, int qw) {
    float inv[4];
#pragma unroll
    for (int r = 0; r < 4; ++r) inv[r] = 1.f / accL[r];
#pragma unroll
    for (int nf = 0; nf < 8; ++nf)
#pragma unroll
      for (int r = 0; r < 4; ++r) {
        const size_t row = (size_t)(b * SEQ + qw + rb + r);
        AO[row * DIMN + h * HDN + nf * 16 + cb] = f2bf(accO[nf][r] * inv[r]);
      }
  };
  epi(accA, accLA, qwA);
  epi(accB, accLB, qwB);
}

// ---------------- launch ----------------
extern "C" void kernel_launch(void* const* d_in, const int* in_sizes, int n_in,
                              void* d_out, int out_size, void* d_ws, size_t ws_size,
                              hipStream_t stream) {
  const float* query = (const float*)d_in[0];
  const float* key_value = (const float*)d_in[1];
  const float* cosT = (const float*)d_in[2];
  const float* sinT = (const float*)d_in[3];
  const float* wq = (const float*)d_in[4];
  const float* bq = (const float*)d_in[5];
  const float* wk = (const float*)d_in[6];
  const float* bk = (const float*)d_in[7];
  const float* wv = (const float*)d_in[8];
  const float* bv = (const float*)d_in[9];
  const float* wo = (const float*)d_in[10];
  const float* bo = (const float*)d_in[11];
  float* out = (float*)d_out;

  const size_t WB = (size_t)DIMN * DIMN * 2;
  const size_t XB = (size_t)MROWS * DIMN * 2;
  char* ws = (char*)d_ws;
  size_t off = 0;
  auto alloc = [&](size_t bytes) {
    char* p = ws + off;
    off += bytes;
    return p;
  };
  // wq..wv..xkv must stay contiguous (fused conv + QKV weight indexing).
  u16* wq_bf = (u16*)alloc(WB);
  u16* wk_bf = (u16*)alloc(WB);
  u16* wv_bf = (u16*)alloc(WB);
  u16* wo_bf = (u16*)alloc(WB);
  u16* xq_bf = (u16*)alloc(XB);
  u16* xkv_bf = (u16*)alloc(XB);
  u16* Qh = (u16*)alloc(XB);
  u16* Kh = (u16*)alloc(XB);
  u16* Vt = (u16*)alloc(XB);
  u16* AO = (u16*)alloc(XB);

  // all six f32->bf16 converts in one launch (dst regions contiguous)
  k_conv6<<<dim3(32768), dim3(256), 0, stream>>>(wq, wk, wv, wo, query, key_value, wq_bf);

  // fused QKV GEMM + bias + RoPE + layout/transpose (one dispatch, 1536 wg)
  k_gemm<1><<<dim3(1536), dim3(256), 0, stream>>>(xq_bf, xkv_bf, wq_bf, bq, bk, bv, Qh, Kh,
                                                  Vt, cosT, sinT);

  k_attn<<<dim3(512), 256, 0, stream>>>(Qh, Kh, Vt, AO);

  k_gemm<0><<<dim3(512), dim3(256), 0, stream>>>(AO, AO, wo_bf, bo, bo, bo, out, nullptr,
                                                 nullptr, nullptr, nullptr);
}

// Round 17
// 271.718 us; speedup vs baseline: 1.6619x; 1.0045x over previous
//
#include <hip/hip_runtime.h>

#define DIMN 2048
#define NH 16
#define HDN 128
#define SEQ 2048
#define BATCH 2
#define MROWS (BATCH * SEQ)  // 4096

typedef unsigned short u16;
using short8 = __attribute__((ext_vector_type(8))) short;
using f32x4 = __attribute__((ext_vector_type(4))) float;

__device__ __forceinline__ u16 f2bf(float f) {
  unsigned int x = __float_as_uint(f);
  unsigned int r = (x + 0x7fffu + ((x >> 16) & 1u)) >> 16;
  return (u16)r;
}
__device__ __forceinline__ float bf2f(u16 u) {
  return __uint_as_float(((unsigned int)u) << 16);
}

typedef const __attribute__((address_space(1))) void* gptr_t;
typedef __attribute__((address_space(3))) void* lptr_t;
__device__ __forceinline__ void gld16(const void* g, void* l) {
  __builtin_amdgcn_global_load_lds((gptr_t)g, (lptr_t)l, 16, 0, 0);
}
__device__ __forceinline__ void waitbar() {
  asm volatile("s_waitcnt vmcnt(0)" ::: "memory");
  __builtin_amdgcn_s_barrier();
  __builtin_amdgcn_sched_barrier(0);
}
__device__ __forceinline__ void barx() {
  asm volatile("" ::: "memory");
  __builtin_amdgcn_s_barrier();
  __builtin_amdgcn_sched_barrier(0);
}

// ---------------- f32 -> bf16 convert (all 6 tensors, one launch) ------------
__global__ void k_conv6(const float* __restrict__ s0, const float* __restrict__ s1,
                        const float* __restrict__ s2, const float* __restrict__ s3,
                        const float* __restrict__ s4, const float* __restrict__ s5,
                        u16* __restrict__ dst) {
  int i = (blockIdx.x * blockDim.x + threadIdx.x) * 4;
  const float* s;
  int off;
  if (i < (1 << 24)) {
    const int which = i >> 22;
    off = i & ((1 << 22) - 1);
    s = (which == 0) ? s0 : (which == 1) ? s1 : (which == 2) ? s2 : s3;
  } else {
    const int j = i - (1 << 24);
    off = j & ((1 << 23) - 1);
    s = (j >> 23) ? s5 : s4;
  }
  float4 v = *(const float4*)(s + off);
  ushort4 o;
  o.x = f2bf(v.x); o.y = f2bf(v.y); o.z = f2bf(v.z); o.w = f2bf(v.w);
  *(ushort4*)(dst + i) = o;
}

// ---------------- GEMM, BK=64 + XOR-swizzled LDS, fused epilogues ----------
// Round-12/16 proven: 128x128 tile, BK=64, single buffer (32KB), bijective
// XCD swizzle.  LDS tiles [128][64] with G4 XOR swizzle (chunk c of row r at
// physical c^(r&7)), staged via pre-swizzled global src (rule 21); zero bank
// conflicts (verified).  Wave (wm,wn) owns rows [wm*64,+64), cols
// {wn*32+(j&1)*16+(j>>1)*64}: rotate-half pair (d,d+64) =
// acc[i][j]/acc[i][j+2] -> RoPE intra-thread.
// MODE 1 (QKV): col group g = n0>>11 picks {A, bias, dest}: g<2 -> bias+RoPE
// -> Qh/Kh [B*H][S][HD]; g==2 -> bias -> Vt [B*H][HD][S] (direct transpose).
// MODE 0: plain f32 + bias (out proj).
template <int MODE>
__global__ __launch_bounds__(256, 4) void k_gemm(const u16* __restrict__ A0,
                                                 const u16* __restrict__ A1,
                                                 const u16* __restrict__ Wb,
                                                 const float* __restrict__ b0,
                                                 const float* __restrict__ b1,
                                                 const float* __restrict__ b2,
                                                 void* __restrict__ o0,
                                                 void* __restrict__ o1,
                                                 void* __restrict__ o2,
                                                 const float* __restrict__ cosT,
                                                 const float* __restrict__ sinT) {
  __shared__ u16 As[128][64];
  __shared__ u16 Bs[128][64];
  const int K = DIMN;
  const int tid = threadIdx.x;
  const int lane = tid & 63;
  const int w = tid >> 6;
  const int wm = w >> 1, wn = w & 1;
  const int kh = lane >> 4;

  int id = blockIdx.x;
  const int nwg = gridDim.x;
  const int cpx = nwg >> 3;
  id = (id & 7) * cpx + (id >> 3);
  const int nbx = (MODE == 1) ? 48 : 16;
  const int n0 = (id % nbx) * 128;
  const int m0 = (id / nbx) * 128;

  const int g = (MODE == 1) ? (n0 >> 11) : 0;
  const u16* A = (MODE == 1 && g > 0) ? A1 : A0;
  const float* bias = (MODE == 1) ? ((g == 0) ? b0 : (g == 1) ? b1 : b2) : b0;
  const int nl = n0 & (DIMN - 1);  // col offset within group (head base)

  // staging: lane l -> row (w*32 + i*8 + (l>>3)), physical chunk (l&7);
  // global source supplies logical chunk (l&7)^(l>>3)
  const int lr = lane >> 3, l8 = lane & 7;
  const u16* gA = A + (size_t)(m0 + w * 32 + lr) * K + (l8 ^ lr) * 8;
  const u16* gB = Wb + (size_t)(n0 + w * 32 + lr) * K + (l8 ^ lr) * 8;

  f32x4 acc[4][4] = {};
  const int cb = lane & 15;
  const int sw = cb & 7;

  for (int k0 = 0; k0 < K; k0 += 64) {
    barx();  // prior compute's LDS reads complete before overwrite
#pragma unroll
    for (int i = 0; i < 4; ++i) {
      gld16(gA + (size_t)i * 8 * K + k0, &As[w * 32 + i * 8][0]);
      gld16(gB + (size_t)i * 8 * K + k0, &Bs[w * 32 + i * 8][0]);
    }
    waitbar();

#pragma unroll
    for (int ks = 0; ks < 2; ++ks) {
      const int ch = ((ks * 4 + kh) ^ sw) * 8;  // swizzled chunk, elem units
      short8 af[4], bfr[4];
#pragma unroll
      for (int i = 0; i < 4; ++i)
        af[i] = *(const short8*)&As[wm * 64 + i * 16 + cb][ch];
#pragma unroll
      for (int j = 0; j < 4; ++j)
        bfr[j] = *(const short8*)&Bs[wn * 32 + (j & 1) * 16 + (j >> 1) * 64 + cb][ch];
#pragma unroll
      for (int i = 0; i < 4; ++i)
#pragma unroll
        for (int j = 0; j < 4; ++j)
          acc[i][j] =
              __builtin_amdgcn_mfma_f32_16x16x32_bf16(af[i], bfr[j], acc[i][j], 0, 0, 0);
    }
  }

  const int rb = kh * 4;

  if (MODE == 0) {
    float* out = (float*)o0;
#pragma unroll
    for (int j = 0; j < 4; ++j) {
      const int col = n0 + wn * 32 + (j & 1) * 16 + (j >> 1) * 64 + cb;
      const float bv = bias[col];
#pragma unroll
      for (int i = 0; i < 4; ++i)
#pragma unroll
        for (int r = 0; r < 4; ++r) {
          const size_t row = (size_t)(m0 + wm * 64 + i * 16 + rb + r);
          out[row * DIMN + col] = acc[i][j][r] + bv;
        }
      __builtin_amdgcn_sched_barrier(0);
    }
  } else if (g == 2) {
    // V: bias, write DIRECTLY transposed to Vt [B*H][HD][S]
    u16* Vt = (u16*)o2;
    const int h_head = nl >> 7;
#pragma unroll
    for (int j = 0; j < 4; ++j) {
      const int d = wn * 32 + (j & 1) * 16 + (j >> 1) * 64 + cb;
      const float bv = bias[nl + d];
#pragma unroll
      for (int i = 0; i < 4; ++i) {
        const int row0 = m0 + wm * 64 + i * 16 + rb;  // 4 consecutive rows
        const int bg = row0 >> 11;
        const int s = row0 & (SEQ - 1);
        ushort4 o;
        o.x = f2bf(acc[i][j][0] + bv);
        o.y = f2bf(acc[i][j][1] + bv);
        o.z = f2bf(acc[i][j][2] + bv);
        o.w = f2bf(acc[i][j][3] + bv);
        *(ushort4*)(Vt + ((size_t)(bg * NH + h_head) * HDN + d) * SEQ + s) = o;
      }
      __builtin_amdgcn_sched_barrier(0);
    }
  } else {
    // Q/K: bias + RoPE (pair intra-thread), write [B*H][S][HD].
    u16* dst = (u16*)((g == 0) ? o0 : o1);
    const int h_head = nl >> 7;
    const int d0 = wn * 32 + cb;
    const float bv10 = bias[nl + d0], bv20 = bias[nl + d0 + 64];
    const float bv11 = bias[nl + d0 + 16], bv21 = bias[nl + d0 + 80];
#pragma unroll
    for (int i = 0; i < 4; ++i) {
#pragma unroll
      for (int r = 0; r < 4; ++r) {
        const int row = m0 + wm * 64 + i * 16 + rb + r;
        const int bg = row >> 11;
        const int s = row & (SEQ - 1);
        u16* base = dst + ((size_t)(bg * NH + h_head) * SEQ + s) * HDN;
        const float* cr = cosT + s * HDN;
        const float* sr = sinT + s * HDN;
#pragma unroll
        for (int jp = 0; jp < 2; ++jp) {
          const int d = d0 + jp * 16;  // d < 64
          float x1 = acc[i][jp][r] + (jp ? bv11 : bv10);
          float x2 = acc[i][jp + 2][r] + (jp ? bv21 : bv20);
          float c = cr[d], sn = sr[d];  // cos[d] == cos[d+64] (concat table)
          base[d] = f2bf(x1 * c - x2 * sn);
          base[d + 64] = f2bf(x2 * c + x1 * sn);
        }
      }
      __builtin_amdgcn_sched_barrier(0);
    }
  }
}

// ---------------- Flash attention (causal), v10 ------------------------------
// Round-15's LDS diet (correctness-verified there) at the spill-free register
// budget: launch_bounds STAYS (256,2) — round-15's 3x slowdown was the
// (256,3) cap forcing accumulator spill (WRITE_SIZE 415MB), not the code.
// LDS: Ks dbuf 32KB + Vs SINGLE 16KB + split-P Ps[4][16][40] 5KB = 54272B
// -> 3 blocks/CU (3x54272 = 162816 <= 163840), regs ~104 -> no spill.
// Per tile: stageV first (oldest 4 loads), stageK(next) behind it; QK^T +
// exp; split P-bounce; vmcnt(4) (V landed, K-prefetch in flight) + barrier;
// PV from Vs.  No online softmax (scores bounded); l = sum exp2 via MFMA
// ones-B.  (bh,p) XCD-locality remap; segs {p, 31-p} share one K/V sweep.
__global__ __launch_bounds__(256, 2) void k_attn(const u16* __restrict__ Qh,
                                                 const u16* __restrict__ Kh,
                                                 const u16* __restrict__ Vt,
                                                 u16* __restrict__ AO) {
  __shared__ u16 Ks[2][64 * 128];
  __shared__ u16 Vs[128 * 64];
  __shared__ u16 Ps[4][16][40];
  const int tid = threadIdx.x, lane = tid & 63, w = tid >> 6;

  const int i0 = blockIdx.x;
  const int xcd = i0 & 7;
  const int j = i0 >> 3;
  const int bh = xcd * 4 + (j >> 4);
  const int p = j & 15;

  const int b = bh >> 4, h = bh & 15;
  const int rb = (lane >> 4) * 4, cb = lane & 15, kh = lane >> 4;
  const int sw = cb & 7;

  int rK[4], cK[4], rV[4], cV[4];
#pragma unroll
  for (int i = 0; i < 4; ++i) {
    const int off = w * 4096 + i * 1024 + lane * 16;
    rK[i] = off >> 8;
    cK[i] = ((off >> 4) & 15) ^ (rK[i] & 7);
    rV[i] = off >> 7;
    cV[i] = ((off >> 4) & 7) ^ (rV[i] & 7);
  }

  const u16* gK = Kh + (size_t)bh * SEQ * HDN;
  const u16* gV = Vt + (size_t)bh * HDN * SEQ;
  const float scale2 = 0.127517435f;  // (1/sqrt(128)) * log2(e)
  const short8 ones8 = {0x3F80, 0x3F80, 0x3F80, 0x3F80, 0x3F80, 0x3F80, 0x3F80, 0x3F80};

  auto stageK = [&](int buf, int kv0) {
    u16* KsB = &Ks[buf][0] + w * 2048;
#pragma unroll
    for (int i = 0; i < 4; ++i)
      gld16(gK + (size_t)(kv0 + rK[i]) * HDN + cK[i] * 8, KsB + i * 512);
  };
  auto stageV = [&](int kv0) {
    u16* VsB = &Vs[0] + w * 2048;
#pragma unroll
    for (int i = 0; i < 4; ++i)
      gld16(gV + (size_t)rV[i] * SEQ + kv0 + cV[i] * 8, VsB + i * 512);
  };
  // mid-tile wait: V (oldest 4 loads/wave) done; K-prefetch stays in flight
  auto midwait = [&](bool kin) {
    if (kin)
      asm volatile("s_waitcnt vmcnt(4)" ::: "memory");
    else
      asm volatile("s_waitcnt vmcnt(0)" ::: "memory");
    __builtin_amdgcn_s_barrier();
    __builtin_amdgcn_sched_barrier(0);
  };

  const int qiA = p, qiB = 31 - p;
  const int qwA = qiA * 64 + w * 16;
  const int qwB = qiB * 64 + w * 16;

  short8 aqA[4], aqB[4];
  {
    const u16* qpA = Qh + ((size_t)bh * SEQ + qwA + cb) * HDN + kh * 8;
    const u16* qpB = Qh + ((size_t)bh * SEQ + qwB + cb) * HDN + kh * 8;
#pragma unroll
    for (int ks = 0; ks < 4; ++ks) {
      aqA[ks] = *(const short8*)(qpA + ks * 32);
      aqB[ks] = *(const short8*)(qpB + ks * 32);
    }
  }

  f32x4 accA[8] = {}, accB[8] = {};
  f32x4 accLA = {}, accLB = {};

  auto expmask = [&](f32x4(&sc)[4], int qw, int kv0, bool masked) {
    if (masked) {
#pragma unroll
      for (int f = 0; f < 4; ++f) {
        const int kva = kv0 + f * 16 + cb;
#pragma unroll
        for (int r = 0; r < 4; ++r)
          sc[f][r] = (kva <= qw + rb + r) ? exp2f(sc[f][r] * scale2) : 0.f;
      }
    } else {
#pragma unroll
      for (int f = 0; f < 4; ++f)
#pragma unroll
        for (int r = 0; r < 4; ++r) sc[f][r] = exp2f(sc[f][r] * scale2);
    }
  };
  // split P bounce: 16x32 buffer reused for the two kk halves (cols 0..31
  // then 32..63); per-wave LDS ops are in-order (round-15 verified).
  auto pbounce = [&](const f32x4(&sc)[4], short8(&pa)[2]) {
#pragma unroll
    for (int kk = 0; kk < 2; ++kk) {
      asm volatile("" ::: "memory");
#pragma unroll
      for (int f = 0; f < 2; ++f)
#pragma unroll
        for (int r = 0; r < 4; ++r)
          Ps[w][rb + r][f * 16 + cb] = f2bf(sc[kk * 2 + f][r]);
      asm volatile("" ::: "memory");
      pa[kk] = *(const short8*)&Ps[w][cb][kh * 8];
      asm volatile("" ::: "memory");
    }
  };

  // single-segment tile (segB only)
  auto tile_single = [&](int kv0, bool masked, const u16* KsB, bool kin) {
    f32x4 sc[4] = {};
    __builtin_amdgcn_s_setprio(1);
#pragma unroll
    for (int f = 0; f < 4; ++f)
#pragma unroll
      for (int ks = 0; ks < 4; ++ks) {
        short8 bk = *(const short8*)(KsB + (f * 16 + cb) * 128 + (((ks * 4 + kh) ^ sw) * 8));
        sc[f] = __builtin_amdgcn_mfma_f32_16x16x32_bf16(aqB[ks], bk, sc[f], 0, 0, 0);
      }
    __builtin_amdgcn_s_setprio(0);
    expmask(sc, qwB, kv0, masked);
    short8 pa[2];
    pbounce(sc, pa);
    midwait(kin);
    __builtin_amdgcn_s_setprio(1);
#pragma unroll
    for (int nf = 0; nf < 8; ++nf)
#pragma unroll
      for (int kk = 0; kk < 2; ++kk) {
        short8 bv = *(const short8*)(&Vs[0] + (nf * 16 + cb) * 64 + (((kk * 4 + kh) ^ sw) * 8));
        accB[nf] = __builtin_amdgcn_mfma_f32_16x16x32_bf16(pa[kk], bv, accB[nf], 0, 0, 0);
      }
#pragma unroll
    for (int kk = 0; kk < 2; ++kk)
      accLB = __builtin_amdgcn_mfma_f32_16x16x32_bf16(pa[kk], ones8, accLB, 0, 0, 0);
    __builtin_amdgcn_s_setprio(0);
  };

  // shared tile: one bk/bv read feeds both segments; segB provably unmasked.
  auto tile_shared = [&](int kv0, bool maskA, const u16* KsB, bool kin) {
    f32x4 scA[4] = {}, scB[4] = {};
    __builtin_amdgcn_s_setprio(1);
#pragma unroll
    for (int f = 0; f < 4; ++f)
#pragma unroll
      for (int ks = 0; ks < 4; ++ks) {
        short8 bk = *(const short8*)(KsB + (f * 16 + cb) * 128 + (((ks * 4 + kh) ^ sw) * 8));
        scB[f] = __builtin_amdgcn_mfma_f32_16x16x32_bf16(aqB[ks], bk, scB[f], 0, 0, 0);
        scA[f] = __builtin_amdgcn_mfma_f32_16x16x32_bf16(aqA[ks], bk, scA[f], 0, 0, 0);
      }
    __builtin_amdgcn_s_setprio(0);
    expmask(scB, qwB, kv0, false);
    expmask(scA, qwA, kv0, maskA);
    short8 paB[2], paA[2];
    pbounce(scB, paB);
    pbounce(scA, paA);
    midwait(kin);
    __builtin_amdgcn_s_setprio(1);
#pragma unroll
    for (int nf = 0; nf < 8; ++nf)
#pragma unroll
      for (int kk = 0; kk < 2; ++kk) {
        short8 bv = *(const short8*)(&Vs[0] + (nf * 16 + cb) * 64 + (((kk * 4 + kh) ^ sw) * 8));
        accB[nf] = __builtin_amdgcn_mfma_f32_16x16x32_bf16(paB[kk], bv, accB[nf], 0, 0, 0);
        accA[nf] = __builtin_amdgcn_mfma_f32_16x16x32_bf16(paA[kk], bv, accA[nf], 0, 0, 0);
      }
#pragma unroll
    for (int kk = 0; kk < 2; ++kk) {
      accLB = __builtin_amdgcn_mfma_f32_16x16x32_bf16(paB[kk], ones8, accLB, 0, 0, 0);
      accLA = __builtin_amdgcn_mfma_f32_16x16x32_bf16(paA[kk], ones8, accLA, 0, 0, 0);
    }
    __builtin_amdgcn_s_setprio(0);
  };

  const int nt = qiB + 1;
  stageK(0, 0);
  waitbar();
  int cur = 0;

  for (int t = 0; t < nt; ++t) {
    const int kv0 = t * 64;
    const bool kin = (t + 1 < nt);
    stageV(kv0);                         // 4 loads/wave (oldest)
    if (kin) stageK(cur ^ 1, kv0 + 64);  // +4 loads (in flight past midwait)

    if (t <= qiA)
      tile_shared(kv0, t == qiA, &Ks[cur][0], kin);
    else
      tile_single(kv0, t == qiB, &Ks[cur][0], kin);

    waitbar();  // drain K-prefetch; all Vs/Ks readers done before overwrite
    cur ^= 1;
  }

  auto epi = [&](f32x4(&accO)[8], f32x4& accL, int qw) {
    float inv[4];
#pragma unroll
    for (int r = 0; r < 4; ++r) inv[r] = 1.f / accL[r];
#pragma unroll
    for (int nf = 0; nf < 8; ++nf)
#pragma unroll
      for (int r = 0; r < 4; ++r) {
        const size_t row = (size_t)(b * SEQ + qw + rb + r);
        AO[row * DIMN + h * HDN + nf * 16 + cb] = f2bf(accO[nf][r] * inv[r]);
      }
  };
  epi(accA, accLA, qwA);
  epi(accB, accLB, qwB);
}

// ---------------- launch ----------------
extern "C" void kernel_launch(void* const* d_in, const int* in_sizes, int n_in,
                              void* d_out, int out_size, void* d_ws, size_t ws_size,
                              hipStream_t stream) {
  const float* query = (const float*)d_in[0];
  const float* key_value = (const float*)d_in[1];
  const float* cosT = (const float*)d_in[2];
  const float* sinT = (const float*)d_in[3];
  const float* wq = (const float*)d_in[4];
  const float* bq = (const float*)d_in[5];
  const float* wk = (const float*)d_in[6];
  const float* bk = (const float*)d_in[7];
  const float* wv = (const float*)d_in[8];
  const float* bv = (const float*)d_in[9];
  const float* wo = (const float*)d_in[10];
  const float* bo = (const float*)d_in[11];
  float* out = (float*)d_out;

  const size_t WB = (size_t)DIMN * DIMN * 2;
  const size_t XB = (size_t)MROWS * DIMN * 2;
  char* ws = (char*)d_ws;
  size_t off = 0;
  auto alloc = [&](size_t bytes) {
    char* p = ws + off;
    off += bytes;
    return p;
  };
  // wq..wv..xkv must stay contiguous (fused conv + QKV weight indexing).
  u16* wq_bf = (u16*)alloc(WB);
  u16* wk_bf = (u16*)alloc(WB);
  u16* wv_bf = (u16*)alloc(WB);
  u16* wo_bf = (u16*)alloc(WB);
  u16* xq_bf = (u16*)alloc(XB);
  u16* xkv_bf = (u16*)alloc(XB);
  u16* Qh = (u16*)alloc(XB);
  u16* Kh = (u16*)alloc(XB);
  u16* Vt = (u16*)alloc(XB);
  u16* AO = (u16*)alloc(XB);

  // all six f32->bf16 converts in one launch (dst regions contiguous)
  k_conv6<<<dim3(32768), dim3(256), 0, stream>>>(wq, wk, wv, wo, query, key_value, wq_bf);

  // fused QKV GEMM + bias + RoPE + layout/transpose (one dispatch, 1536 wg)
  k_gemm<1><<<dim3(1536), dim3(256), 0, stream>>>(xq_bf, xkv_bf, wq_bf, bq, bk, bv, Qh, Kh,
                                                  Vt, cosT, sinT);

  k_attn<<<dim3(512), 256, 0, stream>>>(Qh, Kh, Vt, AO);

  k_gemm<0><<<dim3(512), dim3(256), 0, stream>>>(AO, AO, wo_bf, bo, bo, bo, out, nullptr,
                                                 nullptr, nullptr, nullptr);
}

// Round 18
// 250.091 us; speedup vs baseline: 1.8056x; 1.0865x over previous
//
#include <hip/hip_runtime.h>

#define DIMN 2048
#define NH 16
#define HDN 128
#define SEQ 2048
#define BATCH 2
#define MROWS (BATCH * SEQ)  // 4096

typedef unsigned short u16;
using short8 = __attribute__((ext_vector_type(8))) short;
using f32x4 = __attribute__((ext_vector_type(4))) float;

__device__ __forceinline__ u16 f2bf(float f) {
  unsigned int x = __float_as_uint(f);
  unsigned int r = (x + 0x7fffu + ((x >> 16) & 1u)) >> 16;
  return (u16)r;
}
__device__ __forceinline__ float bf2f(u16 u) {
  return __uint_as_float(((unsigned int)u) << 16);
}

typedef const __attribute__((address_space(1))) void* gptr_t;
typedef __attribute__((address_space(3))) void* lptr_t;
__device__ __forceinline__ void gld16(const void* g, void* l) {
  __builtin_amdgcn_global_load_lds((gptr_t)g, (lptr_t)l, 16, 0, 0);
}
__device__ __forceinline__ void waitbar() {
  asm volatile("s_waitcnt vmcnt(0)" ::: "memory");
  __builtin_amdgcn_s_barrier();
  __builtin_amdgcn_sched_barrier(0);
}
__device__ __forceinline__ void barx() {
  asm volatile("" ::: "memory");
  __builtin_amdgcn_s_barrier();
  __builtin_amdgcn_sched_barrier(0);
}

// ---------------- f32 -> bf16 convert (all 6 tensors, one launch) ------------
__global__ void k_conv6(const float* __restrict__ s0, const float* __restrict__ s1,
                        const float* __restrict__ s2, const float* __restrict__ s3,
                        const float* __restrict__ s4, const float* __restrict__ s5,
                        u16* __restrict__ dst) {
  int i = (blockIdx.x * blockDim.x + threadIdx.x) * 4;
  const float* s;
  int off;
  if (i < (1 << 24)) {
    const int which = i >> 22;
    off = i & ((1 << 22) - 1);
    s = (which == 0) ? s0 : (which == 1) ? s1 : (which == 2) ? s2 : s3;
  } else {
    const int j = i - (1 << 24);
    off = j & ((1 << 23) - 1);
    s = (j >> 23) ? s5 : s4;
  }
  float4 v = *(const float4*)(s + off);
  ushort4 o;
  o.x = f2bf(v.x); o.y = f2bf(v.y); o.z = f2bf(v.z); o.w = f2bf(v.w);
  *(ushort4*)(dst + i) = o;
}

// ---------------- GEMM, BK=64 + XOR-swizzled LDS, fused epilogues ----------
// Round-12/16 proven core; NEW: m-banded XCD walk.  XCD x owns m-panels
// [4x,4x+4); within an XCD the 4 m-blocks of one n-panel run back-to-back
// (m0=(xcd*4+(r&3))*128, n0=(r>>2)*128).  Working set per n-step = 1
// B-panel (512KB) + 4 A-panels (2MB) = 2.5MB -> fits 4MB XCD L2 -> B and A
// each read ~once per XCD (round-17 counter: FETCH 328MB vs 56MB ideal with
// the old n-fastest walk; B was re-fetched 4x).
// LDS tiles [128][64] with G4 XOR swizzle (chunk c of row r at physical
// c^(r&7)), staged via pre-swizzled global src (rule 21); zero conflicts.
// Wave (wm,wn) owns rows [wm*64,+64), cols {wn*32+(j&1)*16+(j>>1)*64}:
// rotate-half pair (d,d+64) = acc[i][j]/acc[i][j+2] -> RoPE intra-thread.
// MODE 1 (QKV): col group g = n0>>11 picks {A, bias, dest}: g<2 -> bias+RoPE
// -> Qh/Kh [B*H][S][HD]; g==2 -> bias -> Vt [B*H][HD][S] (direct transpose).
// MODE 0: plain f32 + bias (out proj).
template <int MODE>
__global__ __launch_bounds__(256, 4) void k_gemm(const u16* __restrict__ A0,
                                                 const u16* __restrict__ A1,
                                                 const u16* __restrict__ Wb,
                                                 const float* __restrict__ b0,
                                                 const float* __restrict__ b1,
                                                 const float* __restrict__ b2,
                                                 void* __restrict__ o0,
                                                 void* __restrict__ o1,
                                                 void* __restrict__ o2,
                                                 const float* __restrict__ cosT,
                                                 const float* __restrict__ sinT) {
  __shared__ u16 As[128][64];
  __shared__ u16 Bs[128][64];
  const int K = DIMN;
  const int tid = threadIdx.x;
  const int lane = tid & 63;
  const int w = tid >> 6;
  const int wm = w >> 1, wn = w & 1;
  const int kh = lane >> 4;

  // m-banded XCD mapping (bijective): xcd owns 4 contiguous m-panels;
  // 4 m-blocks of each n-panel consecutive -> B+A L2-resident per XCD.
  const int bid = blockIdx.x;
  const int xcd = bid & 7;
  const int r_ = bid >> 3;
  const int m0 = (xcd * 4 + (r_ & 3)) * 128;
  const int n0 = (r_ >> 2) * 128;

  const int g = (MODE == 1) ? (n0 >> 11) : 0;
  const u16* A = (MODE == 1 && g > 0) ? A1 : A0;
  const float* bias = (MODE == 1) ? ((g == 0) ? b0 : (g == 1) ? b1 : b2) : b0;
  const int nl = n0 & (DIMN - 1);  // col offset within group (head base)

  // staging: lane l -> row (w*32 + i*8 + (l>>3)), physical chunk (l&7);
  // global source supplies logical chunk (l&7)^(l>>3)
  const int lr = lane >> 3, l8 = lane & 7;
  const u16* gA = A + (size_t)(m0 + w * 32 + lr) * K + (l8 ^ lr) * 8;
  const u16* gB = Wb + (size_t)(n0 + w * 32 + lr) * K + (l8 ^ lr) * 8;

  f32x4 acc[4][4] = {};
  const int cb = lane & 15;
  const int sw = cb & 7;

  for (int k0 = 0; k0 < K; k0 += 64) {
    barx();  // prior compute's LDS reads complete before overwrite
#pragma unroll
    for (int i = 0; i < 4; ++i) {
      gld16(gA + (size_t)i * 8 * K + k0, &As[w * 32 + i * 8][0]);
      gld16(gB + (size_t)i * 8 * K + k0, &Bs[w * 32 + i * 8][0]);
    }
    waitbar();

#pragma unroll
    for (int ks = 0; ks < 2; ++ks) {
      const int ch = ((ks * 4 + kh) ^ sw) * 8;  // swizzled chunk, elem units
      short8 af[4], bfr[4];
#pragma unroll
      for (int i = 0; i < 4; ++i)
        af[i] = *(const short8*)&As[wm * 64 + i * 16 + cb][ch];
#pragma unroll
      for (int j = 0; j < 4; ++j)
        bfr[j] = *(const short8*)&Bs[wn * 32 + (j & 1) * 16 + (j >> 1) * 64 + cb][ch];
#pragma unroll
      for (int i = 0; i < 4; ++i)
#pragma unroll
        for (int j = 0; j < 4; ++j)
          acc[i][j] =
              __builtin_amdgcn_mfma_f32_16x16x32_bf16(af[i], bfr[j], acc[i][j], 0, 0, 0);
    }
  }

  const int rb = kh * 4;

  if (MODE == 0) {
    float* out = (float*)o0;
#pragma unroll
    for (int j = 0; j < 4; ++j) {
      const int col = n0 + wn * 32 + (j & 1) * 16 + (j >> 1) * 64 + cb;
      const float bv = bias[col];
#pragma unroll
      for (int i = 0; i < 4; ++i)
#pragma unroll
        for (int r = 0; r < 4; ++r) {
          const size_t row = (size_t)(m0 + wm * 64 + i * 16 + rb + r);
          out[row * DIMN + col] = acc[i][j][r] + bv;
        }
      __builtin_amdgcn_sched_barrier(0);
    }
  } else if (g == 2) {
    // V: bias, write DIRECTLY transposed to Vt [B*H][HD][S]
    u16* Vt = (u16*)o2;
    const int h_head = nl >> 7;
#pragma unroll
    for (int j = 0; j < 4; ++j) {
      const int d = wn * 32 + (j & 1) * 16 + (j >> 1) * 64 + cb;
      const float bv = bias[nl + d];
#pragma unroll
      for (int i = 0; i < 4; ++i) {
        const int row0 = m0 + wm * 64 + i * 16 + rb;  // 4 consecutive rows
        const int bg = row0 >> 11;
        const int s = row0 & (SEQ - 1);
        ushort4 o;
        o.x = f2bf(acc[i][j][0] + bv);
        o.y = f2bf(acc[i][j][1] + bv);
        o.z = f2bf(acc[i][j][2] + bv);
        o.w = f2bf(acc[i][j][3] + bv);
        *(ushort4*)(Vt + ((size_t)(bg * NH + h_head) * HDN + d) * SEQ + s) = o;
      }
      __builtin_amdgcn_sched_barrier(0);
    }
  } else {
    // Q/K: bias + RoPE (pair intra-thread), write [B*H][S][HD].
    u16* dst = (u16*)((g == 0) ? o0 : o1);
    const int h_head = nl >> 7;
    const int d0 = wn * 32 + cb;
    const float bv10 = bias[nl + d0], bv20 = bias[nl + d0 + 64];
    const float bv11 = bias[nl + d0 + 16], bv21 = bias[nl + d0 + 80];
#pragma unroll
    for (int i = 0; i < 4; ++i) {
#pragma unroll
      for (int r = 0; r < 4; ++r) {
        const int row = m0 + wm * 64 + i * 16 + rb + r;
        const int bg = row >> 11;
        const int s = row & (SEQ - 1);
        u16* base = dst + ((size_t)(bg * NH + h_head) * SEQ + s) * HDN;
        const float* cr = cosT + s * HDN;
        const float* sr = sinT + s * HDN;
#pragma unroll
        for (int jp = 0; jp < 2; ++jp) {
          const int d = d0 + jp * 16;  // d < 64
          float x1 = acc[i][jp][r] + (jp ? bv11 : bv10);
          float x2 = acc[i][jp + 2][r] + (jp ? bv21 : bv20);
          float c = cr[d], sn = sr[d];  // cos[d] == cos[d+64] (concat table)
          base[d] = f2bf(x1 * c - x2 * sn);
          base[d + 64] = f2bf(x2 * c + x1 * sn);
        }
      }
      __builtin_amdgcn_sched_barrier(0);
    }
  }
}

// ---------------- Flash attention (causal), v10 (round-17, kept) -------------
// launch_bounds (256,2) — (256,3) reg-cap spills accumulators (rounds 13/15).
// LDS: Ks dbuf 32KB + Vs SINGLE 16KB + split-P Ps[4][16][40] 5KB = 54272B.
// Per tile: stageV first, stageK(next) behind; QK^T + exp; split P-bounce;
// vmcnt(4)+barrier (V landed, K-prefetch in flight); PV from Vs.  No online
// softmax (scores bounded); l = sum exp2 via MFMA ones-B.  (bh,p) XCD-
// locality remap; segs {p, 31-p} share one K/V sweep.
__global__ __launch_bounds__(256, 2) void k_attn(const u16* __restrict__ Qh,
                                                 const u16* __restrict__ Kh,
                                                 const u16* __restrict__ Vt,
                                                 u16* __restrict__ AO) {
  __shared__ u16 Ks[2][64 * 128];
  __shared__ u16 Vs[128 * 64];
  __shared__ u16 Ps[4][16][40];
  const int tid = threadIdx.x, lane = tid & 63, w = tid >> 6;

  const int i0 = blockIdx.x;
  const int xcd = i0 & 7;
  const int j = i0 >> 3;
  const int bh = xcd * 4 + (j >> 4);
  const int p = j & 15;

  const int b = bh >> 4, h = bh & 15;
  const int rb = (lane >> 4) * 4, cb = lane & 15, kh = lane >> 4;
  const int sw = cb & 7;

  int rK[4], cK[4], rV[4], cV[4];
#pragma unroll
  for (int i = 0; i < 4; ++i) {
    const int off = w * 4096 + i * 1024 + lane * 16;
    rK[i] = off >> 8;
    cK[i] = ((off >> 4) & 15) ^ (rK[i] & 7);
    rV[i] = off >> 7;
    cV[i] = ((off >> 4) & 7) ^ (rV[i] & 7);
  }

  const u16* gK = Kh + (size_t)bh * SEQ * HDN;
  const u16* gV = Vt + (size_t)bh * HDN * SEQ;
  const float scale2 = 0.127517435f;  // (1/sqrt(128)) * log2(e)
  const short8 ones8 = {0x3F80, 0x3F80, 0x3F80, 0x3F80, 0x3F80, 0x3F80, 0x3F80, 0x3F80};

  auto stageK = [&](int buf, int kv0) {
    u16* KsB = &Ks[buf][0] + w * 2048;
#pragma unroll
    for (int i = 0; i < 4; ++i)
      gld16(gK + (size_t)(kv0 + rK[i]) * HDN + cK[i] * 8, KsB + i * 512);
  };
  auto stageV = [&](int kv0) {
    u16* VsB = &Vs[0] + w * 2048;
#pragma unroll
    for (int i = 0; i < 4; ++i)
      gld16(gV + (size_t)rV[i] * SEQ + kv0 + cV[i] * 8, VsB + i * 512);
  };
  auto midwait = [&](bool kin) {
    if (kin)
      asm volatile("s_waitcnt vmcnt(4)" ::: "memory");
    else
      asm volatile("s_waitcnt vmcnt(0)" ::: "memory");
    __builtin_amdgcn_s_barrier();
    __builtin_amdgcn_sched_barrier(0);
  };

  const int qiA = p, qiB = 31 - p;
  const int qwA = qiA * 64 + w * 16;
  const int qwB = qiB * 64 + w * 16;

  short8 aqA[4], aqB[4];
  {
    const u16* qpA = Qh + ((size_t)bh * SEQ + qwA + cb) * HDN + kh * 8;
    const u16* qpB = Qh + ((size_t)bh * SEQ + qwB + cb) * HDN + kh * 8;
#pragma unroll
    for (int ks = 0; ks < 4; ++ks) {
      aqA[ks] = *(const short8*)(qpA + ks * 32);
      aqB[ks] = *(const short8*)(qpB + ks * 32);
    }
  }

  f32x4 accA[8] = {}, accB[8] = {};
  f32x4 accLA = {}, accLB = {};

  auto expmask = [&](f32x4(&sc)[4], int qw, int kv0, bool masked) {
    if (masked) {
#pragma unroll
      for (int f = 0; f < 4; ++f) {
        const int kva = kv0 + f * 16 + cb;
#pragma unroll
        for (int r = 0; r < 4; ++r)
          sc[f][r] = (kva <= qw + rb + r) ? exp2f(sc[f][r] * scale2) : 0.f;
      }
    } else {
#pragma unroll
      for (int f = 0; f < 4; ++f)
#pragma unroll
        for (int r = 0; r < 4; ++r) sc[f][r] = exp2f(sc[f][r] * scale2);
    }
  };
  auto pbounce = [&](const f32x4(&sc)[4], short8(&pa)[2]) {
#pragma unroll
    for (int kk = 0; kk < 2; ++kk) {
      asm volatile("" ::: "memory");
#pragma unroll
      for (int f = 0; f < 2; ++f)
#pragma unroll
        for (int r = 0; r < 4; ++r)
          Ps[w][rb + r][f * 16 + cb] = f2bf(sc[kk * 2 + f][r]);
      asm volatile("" ::: "memory");
      pa[kk] = *(const short8*)&Ps[w][cb][kh * 8];
      asm volatile("" ::: "memory");
    }
  };

  auto tile_single = [&](int kv0, bool masked, const u16* KsB, bool kin) {
    f32x4 sc[4] = {};
    __builtin_amdgcn_s_setprio(1);
#pragma unroll
    for (int f = 0; f < 4; ++f)
#pragma unroll
      for (int ks = 0; ks < 4; ++ks) {
        short8 bk = *(const short8*)(KsB + (f * 16 + cb) * 128 + (((ks * 4 + kh) ^ sw) * 8));
        sc[f] = __builtin_amdgcn_mfma_f32_16x16x32_bf16(aqB[ks], bk, sc[f], 0, 0, 0);
      }
    __builtin_amdgcn_s_setprio(0);
    expmask(sc, qwB, kv0, masked);
    short8 pa[2];
    pbounce(sc, pa);
    midwait(kin);
    __builtin_amdgcn_s_setprio(1);
#pragma unroll
    for (int nf = 0; nf < 8; ++nf)
#pragma unroll
      for (int kk = 0; kk < 2; ++kk) {
        short8 bv = *(const short8*)(&Vs[0] + (nf * 16 + cb) * 64 + (((kk * 4 + kh) ^ sw) * 8));
        accB[nf] = __builtin_amdgcn_mfma_f32_16x16x32_bf16(pa[kk], bv, accB[nf], 0, 0, 0);
      }
#pragma unroll
    for (int kk = 0; kk < 2; ++kk)
      accLB = __builtin_amdgcn_mfma_f32_16x16x32_bf16(pa[kk], ones8, accLB, 0, 0, 0);
    __builtin_amdgcn_s_setprio(0);
  };

  auto tile_shared = [&](int kv0, bool maskA, const u16* KsB, bool kin) {
    f32x4 scA[4] = {}, scB[4] = {};
    __builtin_amdgcn_s_setprio(1);
#pragma unroll
    for (int f = 0; f < 4; ++f)
#pragma unroll
      for (int ks = 0; ks < 4; ++ks) {
        short8 bk = *(const short8*)(KsB + (f * 16 + cb) * 128 + (((ks * 4 + kh) ^ sw) * 8));
        scB[f] = __builtin_amdgcn_mfma_f32_16x16x32_bf16(aqB[ks], bk, scB[f], 0, 0, 0);
        scA[f] = __builtin_amdgcn_mfma_f32_16x16x32_bf16(aqA[ks], bk, scA[f], 0, 0, 0);
      }
    __builtin_amdgcn_s_setprio(0);
    expmask(scB, qwB, kv0, false);
    expmask(scA, qwA, kv0, maskA);
    short8 paB[2], paA[2];
    pbounce(scB, paB);
    pbounce(scA, paA);
    midwait(kin);
    __builtin_amdgcn_s_setprio(1);
#pragma unroll
    for (int nf = 0; nf < 8; ++nf)
#pragma unroll
      for (int kk = 0; kk < 2; ++kk) {
        short8 bv = *(const short8*)(&Vs[0] + (nf * 16 + cb) * 64 + (((kk * 4 + kh) ^ sw) * 8));
        accB[nf] = __builtin_amdgcn_mfma_f32_16x16x32_bf16(paB[kk], bv, accB[nf], 0, 0, 0);
        accA[nf] = __builtin_amdgcn_mfma_f32_16x16x32_bf16(paA[kk], bv, accA[nf], 0, 0, 0);
      }
#pragma unroll
    for (int kk = 0; kk < 2; ++kk) {
      accLB = __builtin_amdgcn_mfma_f32_16x16x32_bf16(paB[kk], ones8, accLB, 0, 0, 0);
      accLA = __builtin_amdgcn_mfma_f32_16x16x32_bf16(paA[kk], ones8, accLA, 0, 0, 0);
    }
    __builtin_amdgcn_s_setprio(0);
  };

  const int nt = qiB + 1;
  stageK(0, 0);
  waitbar();
  int cur = 0;

  for (int t = 0; t < nt; ++t) {
    const int kv0 = t * 64;
    const bool kin = (t + 1 < nt);
    stageV(kv0);                         // 4 loads/wave (oldest)
    if (kin) stageK(cur ^ 1, kv0 + 64);  // +4 loads (in flight past midwait)

    if (t <= qiA)
      tile_shared(kv0, t == qiA, &Ks[cur][0], kin);
    else
      tile_single(kv0, t == qiB, &Ks[cur][0], kin);

    waitbar();  // drain K-prefetch; all Vs/Ks readers done before overwrite
    cur ^= 1;
  }

  auto epi = [&](f32x4(&accO)[8], f32x4& accL, int qw) {
    float inv[4];
#pragma unroll
    for (int r = 0; r < 4; ++r) inv[r] = 1.f / accL[r];
#pragma unroll
    for (int nf = 0; nf < 8; ++nf)
#pragma unroll
      for (int r = 0; r < 4; ++r) {
        const size_t row = (size_t)(b * SEQ + qw + rb + r);
        AO[row * DIMN + h * HDN + nf * 16 + cb] = f2bf(accO[nf][r] * inv[r]);
      }
  };
  epi(accA, accLA, qwA);
  epi(accB, accLB, qwB);
}

// ---------------- launch ----------------
extern "C" void kernel_launch(void* const* d_in, const int* in_sizes, int n_in,
                              void* d_out, int out_size, void* d_ws, size_t ws_size,
                              hipStream_t stream) {
  const float* query = (const float*)d_in[0];
  const float* key_value = (const float*)d_in[1];
  const float* cosT = (const float*)d_in[2];
  const float* sinT = (const float*)d_in[3];
  const float* wq = (const float*)d_in[4];
  const float* bq = (const float*)d_in[5];
  const float* wk = (const float*)d_in[6];
  const float* bk = (const float*)d_in[7];
  const float* wv = (const float*)d_in[8];
  const float* bv = (const float*)d_in[9];
  const float* wo = (const float*)d_in[10];
  const float* bo = (const float*)d_in[11];
  float* out = (float*)d_out;

  const size_t WB = (size_t)DIMN * DIMN * 2;
  const size_t XB = (size_t)MROWS * DIMN * 2;
  char* ws = (char*)d_ws;
  size_t off = 0;
  auto alloc = [&](size_t bytes) {
    char* p = ws + off;
    off += bytes;
    return p;
  };
  // wq..wv..xkv must stay contiguous (fused conv + QKV weight indexing).
  u16* wq_bf = (u16*)alloc(WB);
  u16* wk_bf = (u16*)alloc(WB);
  u16* wv_bf = (u16*)alloc(WB);
  u16* wo_bf = (u16*)alloc(WB);
  u16* xq_bf = (u16*)alloc(XB);
  u16* xkv_bf = (u16*)alloc(XB);
  u16* Qh = (u16*)alloc(XB);
  u16* Kh = (u16*)alloc(XB);
  u16* Vt = (u16*)alloc(XB);
  u16* AO = (u16*)alloc(XB);

  // all six f32->bf16 converts in one launch (dst regions contiguous)
  k_conv6<<<dim3(32768), dim3(256), 0, stream>>>(wq, wk, wv, wo, query, key_value, wq_bf);

  // fused QKV GEMM + bias + RoPE + layout/transpose (one dispatch, 1536 wg)
  k_gemm<1><<<dim3(1536), dim3(256), 0, stream>>>(xq_bf, xkv_bf, wq_bf, bq, bk, bv, Qh, Kh,
                                                  Vt, cosT, sinT);

  k_attn<<<dim3(512), 256, 0, stream>>>(Qh, Kh, Vt, AO);

  k_gemm<0><<<dim3(512), dim3(256), 0, stream>>>(AO, AO, wo_bf, bo, bo, bo, out, nullptr,
                                                 nullptr, nullptr, nullptr);
}